// Round 13
// baseline (317.379 us; speedup 1.0000x reference)
//
#include <hip/hip_runtime.h>
#include <hip/hip_fp16.h>

#define N_NODES 50000
#define N_EDGES 1600000
#define EPLUS   1650000   // edges + self loops
#define HCH 128           // hidden channels (H*C)
#define NB 512            // graphs
#define NCLS 4
#define NBUCK 782         // ceil(N_NODES/64); bucket = dst>>6
#define NSB 256           // scatter blocks for passes A/C
#define PCHUNK 6446       // ceil(EPLUS/NSB)
#define EMAX 3072         // per-bucket padded edge capacity (mean 2176, sd ~46)

typedef unsigned int uint;
typedef unsigned short ushort;

__device__ __forceinline__ float lrelu(float v) { return v > 0.f ? v : 0.2f * v; }

// D = a.lo*b.lo + a.hi*b.hi + c  (f16 pairs, f32 accumulate)
__device__ __forceinline__ float fdot2(uint a, uint b, float c) {
  asm("v_dot2_f32_f16 %0, %1, %2, %0" : "+v"(c) : "v"(a), "v"(b));
  return c;
}

// pack two f32 -> two f16 (RTZ) in one VGPR
__device__ __forceinline__ uint pkrtz(float a, float b) {
  auto v = __builtin_amdgcn_cvt_pkrtz(a, b);
  uint r;
  __builtin_memcpy(&r, &v, 4);
  return r;
}

// ---- pass A: per-block bucket histogram (LDS atomics only) ----
__global__ __launch_bounds__(256) void k_pA(const int* __restrict__ ei,
                                            int* __restrict__ M) {
  __shared__ int lh[NBUCK];
  for (int k = threadIdx.x; k < NBUCK; k += 256) lh[k] = 0;
  __syncthreads();
  int lo = blockIdx.x * PCHUNK;
  int hi = lo + PCHUNK; if (hi > EPLUS) hi = EPLUS;
  for (int e = lo + threadIdx.x; e < hi; e += 256) {
    int dst = (e < N_EDGES) ? ei[N_EDGES + e] : (e - N_EDGES);
    atomicAdd(&lh[dst >> 6], 1);
  }
  __syncthreads();
  for (int k = threadIdx.x; k < NBUCK; k += 256)
    M[blockIdx.x * NBUCK + k] = lh[k];
}

// ---- pass B1: per-bucket scan over the NSB block-counts (one block/bucket) ----
__global__ __launch_bounds__(256) void k_pB1(int* __restrict__ M,
                                             int* __restrict__ tot) {
  __shared__ int sm[256];
  int k = blockIdx.x;            // bucket
  int t = threadIdx.x;           // scatter-block index
  int v = M[t * NBUCK + k];
  sm[t] = v;
  __syncthreads();
  for (int off = 1; off < 256; off <<= 1) {
    int u = (t >= off) ? sm[t - off] : 0;
    __syncthreads();
    sm[t] += u;
    __syncthreads();
  }
  M[t * NBUCK + k] = sm[t] - v;  // within-bucket, over-blocks exclusive prefix
  if (t == 255) tot[k] = sm[255];
}

// ---- pass B2: bucket exclusive scan over 782 totals (1 small block-scan) ----
__global__ __launch_bounds__(1024) void k_pB2(const int* __restrict__ tot,
                                              int* __restrict__ bucketstart) {
  __shared__ int sm[1024];
  int k = threadIdx.x;
  int v = (k < NBUCK) ? tot[k] : 0;
  sm[k] = v;
  __syncthreads();
  for (int off = 1; off < 1024; off <<= 1) {
    int u = (k >= off) ? sm[k - off] : 0;
    __syncthreads();
    sm[k] += u;
    __syncthreads();
  }
  if (k < NBUCK) {
    bucketstart[k] = sm[k] - v;                      // exclusive
    if (k == NBUCK - 1) bucketstart[NBUCK] = sm[k];  // = EPLUS
  }
}

// ---- pass C: scatter edges into bucket-grouped order (LDS atomics only) ----
__global__ __launch_bounds__(256) void k_pC(const int* __restrict__ ei,
                                            const int* __restrict__ M,
                                            const int* __restrict__ bucketstart,
                                            uint* __restrict__ part) {
  __shared__ int lbase[NBUCK];
  __shared__ int lc[NBUCK];
  for (int k = threadIdx.x; k < NBUCK; k += 256) {
    lbase[k] = bucketstart[k] + M[blockIdx.x * NBUCK + k];
    lc[k] = 0;
  }
  __syncthreads();
  int lo = blockIdx.x * PCHUNK;
  int hi = lo + PCHUNK; if (hi > EPLUS) hi = EPLUS;
  for (int e = lo + threadIdx.x; e < hi; e += 256) {
    int src, dst;
    if (e < N_EDGES) { src = ei[e]; dst = ei[N_EDGES + e]; }
    else { src = dst = e - N_EDGES; }
    int b = dst >> 6;
    int p = lbase[b] + atomicAdd(&lc[b], 1);
    part[p] = (uint)src | ((uint)dst << 16);   // both ids < 2^16
  }
}

// Y = X[N,128] @ W[128,128] (fp32 vector ALU). BM=64 rows/block -> grid 782.
// Epilogue: f16-pack h into hbu + es/ed per-head dots from fp32 accumulators.
__global__ __launch_bounds__(256) void k_gemm_fused(const float* __restrict__ X,
                                                    const float* __restrict__ W,
                                                    const float* __restrict__ asrc,
                                                    const float* __restrict__ adst,
                                                    uint* __restrict__ hbu,
                                                    float* __restrict__ es,
                                                    float* __restrict__ ed) {
  __shared__ float As[64][36];
  __shared__ float Bs[32][132];
  int tid = threadIdx.x;
  int r0 = blockIdx.x * 64;
  int tm = tid >> 4;   // 0..15 -> rows tm + 16*i, i<4
  int tn = tid & 15;   // 0..15 -> cols tn*8 .. +7  (all within head tn>>2)
  float acc[4][8];
  #pragma unroll
  for (int i = 0; i < 4; ++i)
    #pragma unroll
    for (int j = 0; j < 8; ++j) acc[i][j] = 0.f;

  for (int kc = 0; kc < 128; kc += 32) {
    #pragma unroll
    for (int i = 0; i < 2; ++i) {          // X tile 64x32
      int q = tid + 256 * i;
      int row = q >> 3;
      int kq = (q & 7) << 2;
      int gr = r0 + row;
      float4 v = make_float4(0.f, 0.f, 0.f, 0.f);
      if (gr < N_NODES) v = *(const float4*)&X[(size_t)gr * 128 + kc + kq];
      *(float4*)&As[row][kq] = v;
    }
    #pragma unroll
    for (int i = 0; i < 4; ++i) {          // W tile 32x128
      int q = tid + 256 * i;
      int kr = q >> 5;
      int nq = (q & 31) << 2;
      float4 v = *(const float4*)&W[(size_t)(kc + kr) * 128 + nq];
      *(float4*)&Bs[kr][nq] = v;
    }
    __syncthreads();
    #pragma unroll 8
    for (int k = 0; k < 32; ++k) {
      float a[4];
      #pragma unroll
      for (int i = 0; i < 4; ++i) a[i] = As[tm + 16 * i][k];
      float4 bq0 = *(const float4*)&Bs[k][tn * 8];
      float4 bq1 = *(const float4*)&Bs[k][tn * 8 + 4];
      float b[8] = {bq0.x, bq0.y, bq0.z, bq0.w, bq1.x, bq1.y, bq1.z, bq1.w};
      #pragma unroll
      for (int i = 0; i < 4; ++i)
        #pragma unroll
        for (int j = 0; j < 8; ++j)
          acc[i][j] = fmaf(a[i], b[j], acc[i][j]);
    }
    __syncthreads();
  }

  float av_s[8], av_d[8];
  #pragma unroll
  for (int j = 0; j < 8; ++j) { av_s[j] = asrc[tn * 8 + j]; av_d[j] = adst[tn * 8 + j]; }
  int head = tn >> 2;
  #pragma unroll
  for (int i = 0; i < 4; ++i) {
    int row = r0 + tm + 16 * i;
    float ps = 0.f, pd = 0.f;
    uint us[8];
    #pragma unroll
    for (int j = 0; j < 8; ++j) {
      float v = acc[i][j];
      ps = fmaf(v, av_s[j], ps);
      pd = fmaf(v, av_d[j], pd);
      us[j] = (uint)__half_as_ushort(__float2half_rn(v));
    }
    ps += __shfl_xor(ps, 1); ps += __shfl_xor(ps, 2);
    pd += __shfl_xor(pd, 1); pd += __shfl_xor(pd, 2);
    if (row < N_NODES) {
      uint4 p;
      p.x = us[0] | (us[1] << 16);
      p.y = us[2] | (us[3] << 16);
      p.z = us[4] | (us[5] << 16);
      p.w = us[6] | (us[7] << 16);
      *(uint4*)&hbu[(size_t)row * 64 + tn * 4] = p;
      if ((tn & 3) == 0) {
        es[row * 4 + head] = ps;
        ed[row * 4 + head] = pd;
      }
    }
  }
}

// Bucket-per-block attention with fused fine-CSR build (replaces k_pD + k_attn).
// Prologue: count 64 dsts, pad-to-8 scan. Phase A (all 256 threads over bucket
// edges): exp-weights once per edge -> scattered f16 LDS arrays + LDS-atomic
// denominators. Phase B: wave handles 16 nodes; per 8 edges one aligned b32
// gives the f16 w-pair, perm+fdot2 as before; 4 gathers in flight per 16.
__global__ __launch_bounds__(256) void k_attn2(const uint* __restrict__ hb,
                                               const float* __restrict__ es,
                                               const float* __restrict__ ed,
                                               const int* __restrict__ bucketstart,
                                               const uint* __restrict__ part,
                                               const float* __restrict__ bias,
                                               float* __restrict__ outp, int do_relu) {
  __shared__ ushort lcol[EMAX];          // src id
  __shared__ ushort lwh[4][EMAX];        // f16 exp-weights per head
  __shared__ float  led[256];            // ed for the 64 bucket nodes
  __shared__ float  lden[256];           // denominators [loc][head]
  __shared__ int dcnt[64], pdstart[64], dc2[64];
  int b = blockIdx.x;
  int n0 = bucketstart[b], n1 = bucketstart[b + 1];
  int t = threadIdx.x;
  if (t < 64) { dcnt[t] = 0; dc2[t] = 0; }
  {
    int gi = b * 256 + t;                // = (b*64+loc)*4 + h, contiguous
    led[t] = (gi < N_NODES * 4) ? ed[gi] : 0.f;
    lden[t] = 0.f;
  }
  __syncthreads();
  for (int i = n0 + t; i < n1; i += 256)
    atomicAdd(&dcnt[(part[i] >> 16) & 63], 1);
  __syncthreads();
  if (t < 64) {
    int v = (dcnt[t] + 7) & ~7;          // pad each node's range to x8
    int run = v;
    #pragma unroll
    for (int off = 1; off < 64; off <<= 1) {
      int u = __shfl_up(run, off);
      if (t >= off) run += u;
    }
    pdstart[t] = run - v;
  }
  __syncthreads();
  // ---- phase A: full-occupancy weight computation + scatter ----
  const char* esb = (const char*)es;
  for (int i = n0 + t; i < n1; i += 256) {
    uint pr = part[i];
    int sc = (int)(pr & 0xffffu);
    int loc = (int)((pr >> 16) & 63u);
    float4 esv = *(const float4*)(esb + ((uint)sc << 4));
    float4 edv = *(const float4*)&led[loc * 4];
    float w0 = __expf(lrelu(esv.x + edv.x));
    float w1 = __expf(lrelu(esv.y + edv.y));
    float w2 = __expf(lrelu(esv.z + edv.z));
    float w3 = __expf(lrelu(esv.w + edv.w));
    atomicAdd(&lden[loc * 4 + 0], w0);
    atomicAdd(&lden[loc * 4 + 1], w1);
    atomicAdd(&lden[loc * 4 + 2], w2);
    atomicAdd(&lden[loc * 4 + 3], w3);
    int pos = pdstart[loc] + atomicAdd(&dc2[loc], 1);
    uint wp01 = pkrtz(w0, w1);
    uint wp23 = pkrtz(w2, w3);
    lcol[pos] = (ushort)sc;
    lwh[0][pos] = (ushort)(wp01 & 0xffffu);
    lwh[1][pos] = (ushort)(wp01 >> 16);
    lwh[2][pos] = (ushort)(wp23 & 0xffffu);
    lwh[3][pos] = (ushort)(wp23 >> 16);
  }
  __syncthreads();
  if (t < 64) {                          // zero the pad slots (w=0, row 0)
    int s = pdstart[t] + dcnt[t];
    int e = pdstart[t] + ((dcnt[t] + 7) & ~7);
    for (int i = s; i < e; ++i) {
      lcol[i] = 0;
      lwh[0][i] = 0; lwh[1][i] = 0; lwh[2][i] = 0; lwh[3][i] = 0;
    }
  }
  __syncthreads();
  // ---- phase B ----
  int lane = t & 63, wv = t >> 6;
  int sub = lane & 15;         // channel-group owner (8 channels)
  int esel = lane >> 4;        // pair selector (0..3)
  int head2 = sub >> 2;
  const char* hbb = (const char*)hb + (uint)sub * 16u;
  const ushort* lw = lwh[head2];

#define ABODY(base) { \
    int e0 = (base) + 2 * esel; \
    uint cpair = *(const uint*)&lcol[e0]; \
    uint wpk = *(const uint*)&lw[e0]; \
    uint so0 = (cpair & 0xffffu) << 8; \
    uint so1 = (cpair >> 16) << 8; \
    uint4 q0 = *(const uint4*)(hbb + so0); \
    uint4 q1 = *(const uint4*)(hbb + so1); \
    acc[0] = fdot2(__builtin_amdgcn_perm(q1.x, q0.x, 0x05040100u), wpk, acc[0]); \
    acc[1] = fdot2(__builtin_amdgcn_perm(q1.x, q0.x, 0x07060302u), wpk, acc[1]); \
    acc[2] = fdot2(__builtin_amdgcn_perm(q1.y, q0.y, 0x05040100u), wpk, acc[2]); \
    acc[3] = fdot2(__builtin_amdgcn_perm(q1.y, q0.y, 0x07060302u), wpk, acc[3]); \
    acc[4] = fdot2(__builtin_amdgcn_perm(q1.z, q0.z, 0x05040100u), wpk, acc[4]); \
    acc[5] = fdot2(__builtin_amdgcn_perm(q1.z, q0.z, 0x07060302u), wpk, acc[5]); \
    acc[6] = fdot2(__builtin_amdgcn_perm(q1.w, q0.w, 0x05040100u), wpk, acc[6]); \
    acc[7] = fdot2(__builtin_amdgcn_perm(q1.w, q0.w, 0x07060302u), wpk, acc[7]); \
  }

  for (int m = 0; m < 16; ++m) {
    int loc = wv * 16 + m;
    int n = b * 64 + loc;
    if (n >= N_NODES) break;
    int ps = pdstart[loc];
    int pc = (dcnt[loc] + 7) & ~7;
    float acc[8];
    #pragma unroll
    for (int j = 0; j < 8; ++j) acc[j] = 0.f;
    int i = 0;
    for (; i + 16 <= pc; i += 16) { ABODY(ps + i); ABODY(ps + i + 8); }
    if (i < pc) ABODY(ps + i);
    #pragma unroll
    for (int j = 0; j < 8; ++j) {
      acc[j] += __shfl_xor(acc[j], 16);
      acc[j] += __shfl_xor(acc[j], 32);
    }
    float den = lden[loc * 4 + head2];
    float inv = 1.0f / (den + 1e-16f);
    if (lane < 32) {
      int half = lane >> 4;
      int c = sub * 8 + half * 4;
      float4 bb = *(const float4*)&bias[c];
      float o0 = acc[half * 4 + 0] * inv + bb.x;
      float o1 = acc[half * 4 + 1] * inv + bb.y;
      float o2 = acc[half * 4 + 2] * inv + bb.z;
      float o3 = acc[half * 4 + 3] * inv + bb.w;
      if (do_relu) {
        o0 = fmaxf(o0, 0.f); o1 = fmaxf(o1, 0.f);
        o2 = fmaxf(o2, 0.f); o3 = fmaxf(o3, 0.f);
      }
      *(float4*)&outp[(size_t)n * 128 + c] = make_float4(o0, o1, o2, o3);
    }
  }
#undef ABODY
}

// one block per graph: mean-pool (binary search on sorted batch) + 128->4 classifier
__global__ __launch_bounds__(128) void k_poolcls(const float* __restrict__ out2,
                                                 const int* __restrict__ batch,
                                                 const float* __restrict__ wc,
                                                 const float* __restrict__ bc,
                                                 float* __restrict__ y) {
  int b = blockIdx.x;
  int c = threadIdx.x;
  int lo = 0, hi = N_NODES;
  while (lo < hi) { int mid = (lo + hi) >> 1; if (batch[mid] < b) lo = mid + 1; else hi = mid; }
  int s = lo;
  lo = s; hi = N_NODES;
  while (lo < hi) { int mid = (lo + hi) >> 1; if (batch[mid] < b + 1) lo = mid + 1; else hi = mid; }
  int e = lo;
  float acc0 = 0.f, acc1 = 0.f, acc2 = 0.f, acc3 = 0.f;
  int nidx = s;
  for (; nidx + 4 <= e; nidx += 4) {
    acc0 += out2[(size_t)nidx * 128 + c];
    acc1 += out2[(size_t)(nidx + 1) * 128 + c];
    acc2 += out2[(size_t)(nidx + 2) * 128 + c];
    acc3 += out2[(size_t)(nidx + 3) * 128 + c];
  }
  for (; nidx < e; ++nidx) acc0 += out2[(size_t)nidx * 128 + c];
  float acc = (acc0 + acc1) + (acc2 + acc3);
  float cnt = (float)(e - s);
  float pooled = acc / fmaxf(cnt, 1.0f);
  float4 wrow = *(const float4*)&wc[c * 4];
  float wj[4] = {wrow.x, wrow.y, wrow.z, wrow.w};
  __shared__ float red[128];
  #pragma unroll
  for (int j = 0; j < 4; ++j) {
    red[c] = pooled * wj[j];
    __syncthreads();
    for (int off = 64; off > 0; off >>= 1) {
      if (c < off) red[c] += red[c + off];
      __syncthreads();
    }
    if (c == 0) y[b * 4 + j] = red[0] + bc[j];
    __syncthreads();
  }
}

extern "C" void kernel_launch(void* const* d_in, const int* in_sizes, int n_in,
                              void* d_out, int out_size, void* d_ws, size_t ws_size,
                              hipStream_t stream) {
  const float* x    = (const float*)d_in[0];
  const int*   ei   = (const int*)d_in[1];
  const int*   batch= (const int*)d_in[2];
  const float* w1   = (const float*)d_in[3];
  const float* as1  = (const float*)d_in[4];
  const float* ad1  = (const float*)d_in[5];
  const float* b1   = (const float*)d_in[6];
  const float* w2   = (const float*)d_in[7];
  const float* as2  = (const float*)d_in[8];
  const float* ad2  = (const float*)d_in[9];
  const float* b2   = (const float*)d_in[10];
  const float* wc   = (const float*)d_in[11];
  const float* bc   = (const float*)d_in[12];
  float* y = (float*)d_out;

  char* ws = (char*)d_ws;
  size_t o = 0;
  auto take = [&](size_t bytes) { void* p = ws + o; o = (o + bytes + 255) & ~(size_t)255; return p; };
  uint*  hbu      = (uint*)take((size_t)N_NODES * 64 * 4);        // f16 h, packed 2/word
  float* obuf     = (float*)take((size_t)N_NODES * HCH * 4);      // fp32 layer outputs
  float* es       = (float*)take((size_t)N_NODES * 4 * 4);
  float* ed       = (float*)take((size_t)N_NODES * 4 * 4);
  int*   M        = (int*)take((size_t)NSB * NBUCK * 4);          // per-block bucket hist/prefix
  int*   tot      = (int*)take((size_t)NBUCK * 4);
  int*   bstart   = (int*)take((size_t)(NBUCK + 1) * 4);
  uint*  part     = (uint*)take((size_t)EPLUS * 4);               // bucket-grouped packed edges

  const int GG = (N_NODES + 63) / 64;       // 782 gemm blocks

  // ---- CSR coarse build (no global returning atomics) ----
  k_pA<<<NSB, 256, 0, stream>>>(ei, M);
  k_pB1<<<NBUCK, 256, 0, stream>>>(M, tot);
  k_pB2<<<1, 1024, 0, stream>>>(tot, bstart);
  k_pC<<<NSB, 256, 0, stream>>>(ei, M, bstart, part);

  // ---- layer 1 ----
  k_gemm_fused<<<GG, 256, 0, stream>>>(x, w1, as1, ad1, hbu, es, ed);
  k_attn2<<<NBUCK, 256, 0, stream>>>(hbu, es, ed, bstart, part, b1, obuf, 1);

  // ---- layer 2 ----
  k_gemm_fused<<<GG, 256, 0, stream>>>(obuf, w2, as2, ad2, hbu, es, ed);
  k_attn2<<<NBUCK, 256, 0, stream>>>(hbu, es, ed, bstart, part, b2, obuf, 0);

  // ---- pool + classifier ----
  k_poolcls<<<NB, 128, 0, stream>>>(obuf, batch, wc, bc, y);
}

// Round 14
// 249.936 us; speedup vs baseline: 1.2698x; 1.2698x over previous
//
#include <hip/hip_runtime.h>
#include <hip/hip_fp16.h>

#define N_NODES 50000
#define N_EDGES 1600000
#define EPLUS   1650000   // edges + self loops
#define HCH 128           // hidden channels (H*C)
#define NB 512            // graphs
#define NCLS 4
#define NBUCK 782         // ceil(N_NODES/64); bucket = dst>>6
#define NSB 256           // scatter blocks for passes A/C
#define PCHUNK 6446       // ceil(EPLUS/NSB)

typedef unsigned int uint;

__device__ __forceinline__ float lrelu(float v) { return v > 0.f ? v : 0.2f * v; }

// D = a.lo*b.lo + a.hi*b.hi + c  (f16 pairs, f32 accumulate)
__device__ __forceinline__ float fdot2(uint a, uint b, float c) {
  asm("v_dot2_f32_f16 %0, %1, %2, %0" : "+v"(c) : "v"(a), "v"(b));
  return c;
}

// pack two f32 -> two f16 (RTZ) in one VGPR
__device__ __forceinline__ uint pkrtz(float a, float b) {
  auto v = __builtin_amdgcn_cvt_pkrtz(a, b);
  uint r;
  __builtin_memcpy(&r, &v, 4);
  return r;
}

// ---- pass A: per-block bucket histogram (LDS atomics only) ----
__global__ __launch_bounds__(256) void k_pA(const int* __restrict__ ei,
                                            int* __restrict__ M) {
  __shared__ int lh[NBUCK];
  for (int k = threadIdx.x; k < NBUCK; k += 256) lh[k] = 0;
  __syncthreads();
  int lo = blockIdx.x * PCHUNK;
  int hi = lo + PCHUNK; if (hi > EPLUS) hi = EPLUS;
  for (int e = lo + threadIdx.x; e < hi; e += 256) {
    int dst = (e < N_EDGES) ? ei[N_EDGES + e] : (e - N_EDGES);
    atomicAdd(&lh[dst >> 6], 1);
  }
  __syncthreads();
  for (int k = threadIdx.x; k < NBUCK; k += 256)
    M[blockIdx.x * NBUCK + k] = lh[k];
}

// ---- pass B1: per-bucket scan over the NSB block-counts (one block/bucket) ----
__global__ __launch_bounds__(256) void k_pB1(int* __restrict__ M,
                                             int* __restrict__ tot) {
  __shared__ int sm[256];
  int k = blockIdx.x;            // bucket
  int t = threadIdx.x;           // scatter-block index
  int v = M[t * NBUCK + k];
  sm[t] = v;
  __syncthreads();
  for (int off = 1; off < 256; off <<= 1) {
    int u = (t >= off) ? sm[t - off] : 0;
    __syncthreads();
    sm[t] += u;
    __syncthreads();
  }
  M[t * NBUCK + k] = sm[t] - v;  // within-bucket, over-blocks exclusive prefix
  if (t == 255) tot[k] = sm[255];
}

// ---- pass B2: bucket exclusive scan over 782 totals (1 small block-scan) ----
__global__ __launch_bounds__(1024) void k_pB2(const int* __restrict__ tot,
                                              int* __restrict__ bucketstart) {
  __shared__ int sm[1024];
  int k = threadIdx.x;
  int v = (k < NBUCK) ? tot[k] : 0;
  sm[k] = v;
  __syncthreads();
  for (int off = 1; off < 1024; off <<= 1) {
    int u = (k >= off) ? sm[k - off] : 0;
    __syncthreads();
    sm[k] += u;
    __syncthreads();
  }
  if (k < NBUCK) {
    bucketstart[k] = sm[k] - v;                      // exclusive
    if (k == NBUCK - 1) bucketstart[NBUCK] = sm[k];  // = EPLUS
  }
}

// ---- pass C: scatter edges into bucket-grouped order (LDS atomics only) ----
__global__ __launch_bounds__(256) void k_pC(const int* __restrict__ ei,
                                            const int* __restrict__ M,
                                            const int* __restrict__ bucketstart,
                                            uint* __restrict__ part) {
  __shared__ int lbase[NBUCK];
  __shared__ int lc[NBUCK];
  for (int k = threadIdx.x; k < NBUCK; k += 256) {
    lbase[k] = bucketstart[k] + M[blockIdx.x * NBUCK + k];
    lc[k] = 0;
  }
  __syncthreads();
  int lo = blockIdx.x * PCHUNK;
  int hi = lo + PCHUNK; if (hi > EPLUS) hi = EPLUS;
  for (int e = lo + threadIdx.x; e < hi; e += 256) {
    int src, dst;
    if (e < N_EDGES) { src = ei[e]; dst = ei[N_EDGES + e]; }
    else { src = dst = e - N_EDGES; }
    int b = dst >> 6;
    int p = lbase[b] + atomicAdd(&lc[b], 1);
    part[p] = (uint)src | ((uint)dst << 16);   // both ids < 2^16
  }
}

// ---- pass D: per-bucket fine CSR (64 dsts) via LDS counters + wave scan ----
__global__ __launch_bounds__(256) void k_pD(const uint* __restrict__ part,
                                            const int* __restrict__ bucketstart,
                                            int* __restrict__ rowstart,
                                            int* __restrict__ col) {
  __shared__ int dcnt[64], dstart[64], dc2[64];
  int b = blockIdx.x;
  int n0 = bucketstart[b], n1 = bucketstart[b + 1];
  int t = threadIdx.x;
  if (t < 64) { dcnt[t] = 0; dc2[t] = 0; }
  __syncthreads();
  for (int i = n0 + t; i < n1; i += 256)
    atomicAdd(&dcnt[(part[i] >> 16) & 63], 1);
  __syncthreads();
  if (t < 64) {
    int v = dcnt[t];
    int run = v;
    #pragma unroll
    for (int off = 1; off < 64; off <<= 1) {
      int u = __shfl_up(run, off);
      if (t >= off) run += u;
    }
    dstart[t] = run - v;   // exclusive within bucket
    int node = b * 64 + t;
    if (node < N_NODES) rowstart[node] = n0 + run - v;
  }
  if (b == NBUCK - 1 && t == 0) rowstart[N_NODES] = n1;  // = EPLUS
  __syncthreads();
  for (int i = n0 + t; i < n1; i += 256) {
    uint pr = part[i];
    int loc = (pr >> 16) & 63;
    int pos = n0 + dstart[loc] + atomicAdd(&dc2[loc], 1);
    col[pos] = (int)(pr & 0xffffu);
  }
}

// Y = X[N,128] @ W[128,128] (fp32 vector ALU). BM=64 rows/block -> grid 782.
// Epilogue: f16-pack h into hbu + es/ed per-head dots from fp32 accumulators.
__global__ __launch_bounds__(256) void k_gemm_fused(const float* __restrict__ X,
                                                    const float* __restrict__ W,
                                                    const float* __restrict__ asrc,
                                                    const float* __restrict__ adst,
                                                    uint* __restrict__ hbu,
                                                    float* __restrict__ es,
                                                    float* __restrict__ ed) {
  __shared__ float As[64][36];
  __shared__ float Bs[32][132];
  int tid = threadIdx.x;
  int r0 = blockIdx.x * 64;
  int tm = tid >> 4;   // 0..15 -> rows tm + 16*i, i<4
  int tn = tid & 15;   // 0..15 -> cols tn*8 .. +7  (all within head tn>>2)
  float acc[4][8];
  #pragma unroll
  for (int i = 0; i < 4; ++i)
    #pragma unroll
    for (int j = 0; j < 8; ++j) acc[i][j] = 0.f;

  for (int kc = 0; kc < 128; kc += 32) {
    #pragma unroll
    for (int i = 0; i < 2; ++i) {          // X tile 64x32
      int q = tid + 256 * i;
      int row = q >> 3;
      int kq = (q & 7) << 2;
      int gr = r0 + row;
      float4 v = make_float4(0.f, 0.f, 0.f, 0.f);
      if (gr < N_NODES) v = *(const float4*)&X[(size_t)gr * 128 + kc + kq];
      *(float4*)&As[row][kq] = v;
    }
    #pragma unroll
    for (int i = 0; i < 4; ++i) {          // W tile 32x128
      int q = tid + 256 * i;
      int kr = q >> 5;
      int nq = (q & 31) << 2;
      float4 v = *(const float4*)&W[(size_t)(kc + kr) * 128 + nq];
      *(float4*)&Bs[kr][nq] = v;
    }
    __syncthreads();
    #pragma unroll 8
    for (int k = 0; k < 32; ++k) {
      float a[4];
      #pragma unroll
      for (int i = 0; i < 4; ++i) a[i] = As[tm + 16 * i][k];
      float4 bq0 = *(const float4*)&Bs[k][tn * 8];
      float4 bq1 = *(const float4*)&Bs[k][tn * 8 + 4];
      float b[8] = {bq0.x, bq0.y, bq0.z, bq0.w, bq1.x, bq1.y, bq1.z, bq1.w};
      #pragma unroll
      for (int i = 0; i < 4; ++i)
        #pragma unroll
        for (int j = 0; j < 8; ++j)
          acc[i][j] = fmaf(a[i], b[j], acc[i][j]);
    }
    __syncthreads();
  }

  // epilogue: f16 pack (RNE) + per-head attention dots (exact fp32)
  float av_s[8], av_d[8];
  #pragma unroll
  for (int j = 0; j < 8; ++j) { av_s[j] = asrc[tn * 8 + j]; av_d[j] = adst[tn * 8 + j]; }
  int head = tn >> 2;
  #pragma unroll
  for (int i = 0; i < 4; ++i) {
    int row = r0 + tm + 16 * i;
    float ps = 0.f, pd = 0.f;
    uint us[8];
    #pragma unroll
    for (int j = 0; j < 8; ++j) {
      float v = acc[i][j];
      ps = fmaf(v, av_s[j], ps);
      pd = fmaf(v, av_d[j], pd);
      us[j] = (uint)__half_as_ushort(__float2half_rn(v));
    }
    // reduce over the 4 threads (same tm, same head): lanes base-aligned to 4
    ps += __shfl_xor(ps, 1); ps += __shfl_xor(ps, 2);
    pd += __shfl_xor(pd, 1); pd += __shfl_xor(pd, 2);
    if (row < N_NODES) {
      uint4 p;
      p.x = us[0] | (us[1] << 16);
      p.y = us[2] | (us[3] << 16);
      p.z = us[4] | (us[5] << 16);
      p.w = us[6] | (us[7] << 16);
      *(uint4*)&hbu[(size_t)row * 64 + tn * 4] = p;
      if ((tn & 3) == 0) {
        es[row * 4 + head] = ps;
        ed[row * 4 + head] = pd;
      }
    }
  }
}

// one wave per destination node. Phase A: lanes parallel over <=64 edges,
// exp-weights computed once per edge, stashed in LDS, denominator per-lane
// float4. Phase B: 16 lanes own 8 channels of one edge (uint4 = 8 f16);
// 16 edges per iteration = 4 independent dwordx4 gathers in flight (MLP);
// channel-pairs across edge pairs built with v_perm_b32 and multiplied with
// one v_dot2_f32_f16 per channel. Padded slots have w=0 (contribute nothing).
__global__ __launch_bounds__(256) void k_attn(const uint* __restrict__ hb,
                                              const float* __restrict__ es,
                                              const float* __restrict__ ed,
                                              const int* __restrict__ rowstart,
                                              const int* __restrict__ col,
                                              const float* __restrict__ bias,
                                              float* __restrict__ outp, int do_relu) {
  __shared__ float swv[4][4 * 68];   // [wave][head*68 + edge]
  __shared__ int   ssc[4][64];       // [wave][edge] = src<<8 (byte offset of h row)
  int lane = threadIdx.x & 63;
  int wv = threadIdx.x >> 6;
  int n = blockIdx.x * 4 + wv;
  if (n >= N_NODES) return;
  int s = rowstart[n], t = rowstart[n + 1];
  int sub = lane & 15;         // channel-group owner (8 channels)
  int esel = lane >> 4;        // edge-in-group selector (0..3)
  int head2 = sub >> 2;        // head of this lane's 8 channels
  float4 edv = *(const float4*)&ed[n * 4];
  const char* hbb = (const char*)hb + (uint)sub * 16u;   // lane's 16B slice
  const char* esb = (const char*)es;
  float* wv0 = swv[wv];
  int* sc0 = ssc[wv];

  float4 denv = make_float4(0.f, 0.f, 0.f, 0.f);
  float acc[8];
  #pragma unroll
  for (int j = 0; j < 8; ++j) acc[j] = 0.f;

  for (int base = s; base < t; base += 64) {
    int nthis = t - base; if (nthis > 64) nthis = 64;
    int npad = (nthis + 15) & ~15;
    // ---- phase A ----
    if (lane < nthis) {
      int sc = col[base + lane];
      float4 esv = *(const float4*)(esb + ((uint)sc << 4));
      float w0 = __expf(lrelu(esv.x + edv.x));
      float w1 = __expf(lrelu(esv.y + edv.y));
      float w2 = __expf(lrelu(esv.z + edv.z));
      float w3 = __expf(lrelu(esv.w + edv.w));
      denv.x += w0; denv.y += w1; denv.z += w2; denv.w += w3;
      wv0[0 * 68 + lane] = w0;
      wv0[1 * 68 + lane] = w1;
      wv0[2 * 68 + lane] = w2;
      wv0[3 * 68 + lane] = w3;
      sc0[lane] = sc << 8;
    } else if (lane < npad) {
      wv0[0 * 68 + lane] = 0.f;
      wv0[1 * 68 + lane] = 0.f;
      wv0[2 * 68 + lane] = 0.f;
      wv0[3 * 68 + lane] = 0.f;
      sc0[lane] = 0;
    }
    asm volatile("s_waitcnt lgkmcnt(0)" ::: "memory");
    // ---- phase B: 16 edges per iteration (4 gathers in flight) ----
    __builtin_amdgcn_s_setprio(1);
    for (int i = 0; i < npad; i += 16) {
      int e0 = i + esel, e1 = e0 + 4, e2 = e0 + 8, e3 = e0 + 12;
      float w0 = wv0[head2 * 68 + e0];
      float w1 = wv0[head2 * 68 + e1];
      float w2 = wv0[head2 * 68 + e2];
      float w3 = wv0[head2 * 68 + e3];
      int so0 = sc0[e0], so1 = sc0[e1], so2 = sc0[e2], so3 = sc0[e3];
      uint4 q0 = *(const uint4*)(hbb + (uint)so0);
      uint4 q1 = *(const uint4*)(hbb + (uint)so1);
      uint4 q2 = *(const uint4*)(hbb + (uint)so2);
      uint4 q3 = *(const uint4*)(hbb + (uint)so3);
      uint wa = pkrtz(w0, w1);
      uint wb = pkrtz(w2, w3);
      acc[0] = fdot2(__builtin_amdgcn_perm(q1.x, q0.x, 0x05040100u), wa, acc[0]);
      acc[1] = fdot2(__builtin_amdgcn_perm(q1.x, q0.x, 0x07060302u), wa, acc[1]);
      acc[2] = fdot2(__builtin_amdgcn_perm(q1.y, q0.y, 0x05040100u), wa, acc[2]);
      acc[3] = fdot2(__builtin_amdgcn_perm(q1.y, q0.y, 0x07060302u), wa, acc[3]);
      acc[4] = fdot2(__builtin_amdgcn_perm(q1.z, q0.z, 0x05040100u), wa, acc[4]);
      acc[5] = fdot2(__builtin_amdgcn_perm(q1.z, q0.z, 0x07060302u), wa, acc[5]);
      acc[6] = fdot2(__builtin_amdgcn_perm(q1.w, q0.w, 0x05040100u), wa, acc[6]);
      acc[7] = fdot2(__builtin_amdgcn_perm(q1.w, q0.w, 0x07060302u), wa, acc[7]);
      acc[0] = fdot2(__builtin_amdgcn_perm(q3.x, q2.x, 0x05040100u), wb, acc[0]);
      acc[1] = fdot2(__builtin_amdgcn_perm(q3.x, q2.x, 0x07060302u), wb, acc[1]);
      acc[2] = fdot2(__builtin_amdgcn_perm(q3.y, q2.y, 0x05040100u), wb, acc[2]);
      acc[3] = fdot2(__builtin_amdgcn_perm(q3.y, q2.y, 0x07060302u), wb, acc[3]);
      acc[4] = fdot2(__builtin_amdgcn_perm(q3.z, q2.z, 0x05040100u), wb, acc[4]);
      acc[5] = fdot2(__builtin_amdgcn_perm(q3.z, q2.z, 0x07060302u), wb, acc[5]);
      acc[6] = fdot2(__builtin_amdgcn_perm(q3.w, q2.w, 0x05040100u), wb, acc[6]);
      acc[7] = fdot2(__builtin_amdgcn_perm(q3.w, q2.w, 0x07060302u), wb, acc[7]);
    }
    __builtin_amdgcn_s_setprio(0);
  }
  // reduce partial sums across the 4 edge-selector groups
  #pragma unroll
  for (int j = 0; j < 8; ++j) {
    acc[j] += __shfl_xor(acc[j], 16);
    acc[j] += __shfl_xor(acc[j], 32);
  }
  // reduce denominator across lanes (once per node)
  #pragma unroll
  for (int off = 1; off < 64; off <<= 1) {
    denv.x += __shfl_xor(denv.x, off);
    denv.y += __shfl_xor(denv.y, off);
    denv.z += __shfl_xor(denv.z, off);
    denv.w += __shfl_xor(denv.w, off);
  }
  float den = (head2 & 2) ? ((head2 & 1) ? denv.w : denv.z)
                          : ((head2 & 1) ? denv.y : denv.x);
  float inv = 1.0f / (den + 1e-16f);
  if (lane < 32) {
    int half = lane >> 4;            // 0 or 1
    int c = sub * 8 + half * 4;
    float4 bb = *(const float4*)&bias[c];
    float o0 = acc[half * 4 + 0] * inv + bb.x;
    float o1 = acc[half * 4 + 1] * inv + bb.y;
    float o2 = acc[half * 4 + 2] * inv + bb.z;
    float o3 = acc[half * 4 + 3] * inv + bb.w;
    if (do_relu) {
      o0 = fmaxf(o0, 0.f); o1 = fmaxf(o1, 0.f);
      o2 = fmaxf(o2, 0.f); o3 = fmaxf(o3, 0.f);
    }
    *(float4*)&outp[(size_t)n * 128 + c] = make_float4(o0, o1, o2, o3);
  }
}

// one block per graph: mean-pool (binary search on sorted batch) + 128->4 classifier
__global__ __launch_bounds__(128) void k_poolcls(const float* __restrict__ out2,
                                                 const int* __restrict__ batch,
                                                 const float* __restrict__ wc,
                                                 const float* __restrict__ bc,
                                                 float* __restrict__ y) {
  int b = blockIdx.x;
  int c = threadIdx.x;
  int lo = 0, hi = N_NODES;
  while (lo < hi) { int mid = (lo + hi) >> 1; if (batch[mid] < b) lo = mid + 1; else hi = mid; }
  int s = lo;
  lo = s; hi = N_NODES;
  while (lo < hi) { int mid = (lo + hi) >> 1; if (batch[mid] < b + 1) lo = mid + 1; else hi = mid; }
  int e = lo;
  float acc0 = 0.f, acc1 = 0.f, acc2 = 0.f, acc3 = 0.f;
  int nidx = s;
  for (; nidx + 4 <= e; nidx += 4) {
    acc0 += out2[(size_t)nidx * 128 + c];
    acc1 += out2[(size_t)(nidx + 1) * 128 + c];
    acc2 += out2[(size_t)(nidx + 2) * 128 + c];
    acc3 += out2[(size_t)(nidx + 3) * 128 + c];
  }
  for (; nidx < e; ++nidx) acc0 += out2[(size_t)nidx * 128 + c];
  float acc = (acc0 + acc1) + (acc2 + acc3);
  float cnt = (float)(e - s);
  float pooled = acc / fmaxf(cnt, 1.0f);
  float4 wrow = *(const float4*)&wc[c * 4];
  float wj[4] = {wrow.x, wrow.y, wrow.z, wrow.w};
  __shared__ float red[128];
  #pragma unroll
  for (int j = 0; j < 4; ++j) {
    red[c] = pooled * wj[j];
    __syncthreads();
    for (int off = 64; off > 0; off >>= 1) {
      if (c < off) red[c] += red[c + off];
      __syncthreads();
    }
    if (c == 0) y[b * 4 + j] = red[0] + bc[j];
    __syncthreads();
  }
}

extern "C" void kernel_launch(void* const* d_in, const int* in_sizes, int n_in,
                              void* d_out, int out_size, void* d_ws, size_t ws_size,
                              hipStream_t stream) {
  const float* x    = (const float*)d_in[0];
  const int*   ei   = (const int*)d_in[1];
  const int*   batch= (const int*)d_in[2];
  const float* w1   = (const float*)d_in[3];
  const float* as1  = (const float*)d_in[4];
  const float* ad1  = (const float*)d_in[5];
  const float* b1   = (const float*)d_in[6];
  const float* w2   = (const float*)d_in[7];
  const float* as2  = (const float*)d_in[8];
  const float* ad2  = (const float*)d_in[9];
  const float* b2   = (const float*)d_in[10];
  const float* wc   = (const float*)d_in[11];
  const float* bc   = (const float*)d_in[12];
  float* y = (float*)d_out;

  char* ws = (char*)d_ws;
  size_t o = 0;
  auto take = [&](size_t bytes) { void* p = ws + o; o = (o + bytes + 255) & ~(size_t)255; return p; };
  uint*  hbu      = (uint*)take((size_t)N_NODES * 64 * 4);        // f16 h, packed 2/word
  float* obuf     = (float*)take((size_t)N_NODES * HCH * 4);      // fp32 layer outputs
  float* es       = (float*)take((size_t)N_NODES * 4 * 4);
  float* ed       = (float*)take((size_t)N_NODES * 4 * 4);
  int*   M        = (int*)take((size_t)NSB * NBUCK * 4);          // per-block bucket hist/prefix
  int*   tot      = (int*)take((size_t)NBUCK * 4);
  int*   bstart   = (int*)take((size_t)(NBUCK + 1) * 4);
  uint*  part     = (uint*)take((size_t)EPLUS * 4);               // bucket-grouped packed edges
  int*   rowstart = (int*)take((size_t)(N_NODES + 1) * 4);
  int*   col      = (int*)take((size_t)EPLUS * 4);

  const int GW = N_NODES / 4;               // 12500 wave-per-node
  const int GG = (N_NODES + 63) / 64;       // 782 gemm blocks

  // ---- CSR build (no global returning atomics; scan parallel across CUs) ----
  k_pA<<<NSB, 256, 0, stream>>>(ei, M);
  k_pB1<<<NBUCK, 256, 0, stream>>>(M, tot);
  k_pB2<<<1, 1024, 0, stream>>>(tot, bstart);
  k_pC<<<NSB, 256, 0, stream>>>(ei, M, bstart, part);
  k_pD<<<NBUCK, 256, 0, stream>>>(part, bstart, rowstart, col);

  // ---- layer 1 ----
  k_gemm_fused<<<GG, 256, 0, stream>>>(x, w1, as1, ad1, hbu, es, ed);
  k_attn<<<GW, 256, 0, stream>>>(hbu, es, ed, rowstart, col, b1, obuf, 1);

  // ---- layer 2 ----
  k_gemm_fused<<<GG, 256, 0, stream>>>(obuf, w2, as2, ad2, hbu, es, ed);
  k_attn<<<GW, 256, 0, stream>>>(hbu, es, ed, rowstart, col, b2, obuf, 0);

  // ---- pool + classifier ----
  k_poolcls<<<NB, 128, 0, stream>>>(obuf, batch, wc, bc, y);
}

// Round 15
// 239.479 us; speedup vs baseline: 1.3253x; 1.0437x over previous
//
#include <hip/hip_runtime.h>
#include <hip/hip_fp16.h>

#define N_NODES 50000
#define N_EDGES 1600000
#define EPLUS   1650000   // edges + self loops
#define HCH 128           // hidden channels (H*C)
#define NB 512            // graphs
#define NCLS 4
#define NBUCK 782         // ceil(N_NODES/64); bucket = dst>>6
#define NSB 256           // scatter blocks for passes A/C
#define PCHUNK 6446       // ceil(EPLUS/NSB)

typedef unsigned int uint;

__device__ __forceinline__ float lrelu(float v) { return v > 0.f ? v : 0.2f * v; }

// D = a.lo*b.lo + a.hi*b.hi + c  (f16 pairs, f32 accumulate)
__device__ __forceinline__ float fdot2(uint a, uint b, float c) {
  asm("v_dot2_f32_f16 %0, %1, %2, %0" : "+v"(c) : "v"(a), "v"(b));
  return c;
}

// pack two f32 -> two f16 (RTZ) in one VGPR
__device__ __forceinline__ uint pkrtz(float a, float b) {
  auto v = __builtin_amdgcn_cvt_pkrtz(a, b);
  uint r;
  __builtin_memcpy(&r, &v, 4);
  return r;
}

// pack two f32 -> two f16 (RNE)
__device__ __forceinline__ uint pkrn(float a, float b) {
  return (uint)__half_as_ushort(__float2half_rn(a)) |
         ((uint)__half_as_ushort(__float2half_rn(b)) << 16);
}

// ---- pass A: per-block bucket histogram (LDS atomics only) ----
__global__ __launch_bounds__(256) void k_pA(const int* __restrict__ ei,
                                            int* __restrict__ M) {
  __shared__ int lh[NBUCK];
  for (int k = threadIdx.x; k < NBUCK; k += 256) lh[k] = 0;
  __syncthreads();
  int lo = blockIdx.x * PCHUNK;
  int hi = lo + PCHUNK; if (hi > EPLUS) hi = EPLUS;
  for (int e = lo + threadIdx.x; e < hi; e += 256) {
    int dst = (e < N_EDGES) ? ei[N_EDGES + e] : (e - N_EDGES);
    atomicAdd(&lh[dst >> 6], 1);
  }
  __syncthreads();
  for (int k = threadIdx.x; k < NBUCK; k += 256)
    M[blockIdx.x * NBUCK + k] = lh[k];
}

// ---- pass B1: per-bucket scan over the NSB block-counts (one block/bucket) ----
__global__ __launch_bounds__(256) void k_pB1(int* __restrict__ M,
                                             int* __restrict__ tot) {
  __shared__ int sm[256];
  int k = blockIdx.x;            // bucket
  int t = threadIdx.x;           // scatter-block index
  int v = M[t * NBUCK + k];
  sm[t] = v;
  __syncthreads();
  for (int off = 1; off < 256; off <<= 1) {
    int u = (t >= off) ? sm[t - off] : 0;
    __syncthreads();
    sm[t] += u;
    __syncthreads();
  }
  M[t * NBUCK + k] = sm[t] - v;  // within-bucket, over-blocks exclusive prefix
  if (t == 255) tot[k] = sm[255];
}

// ---- pass B2: bucket exclusive scan over 782 totals (1 small block-scan) ----
__global__ __launch_bounds__(1024) void k_pB2(const int* __restrict__ tot,
                                              int* __restrict__ bucketstart) {
  __shared__ int sm[1024];
  int k = threadIdx.x;
  int v = (k < NBUCK) ? tot[k] : 0;
  sm[k] = v;
  __syncthreads();
  for (int off = 1; off < 1024; off <<= 1) {
    int u = (k >= off) ? sm[k - off] : 0;
    __syncthreads();
    sm[k] += u;
    __syncthreads();
  }
  if (k < NBUCK) {
    bucketstart[k] = sm[k] - v;                      // exclusive
    if (k == NBUCK - 1) bucketstart[NBUCK] = sm[k];  // = EPLUS
  }
}

// ---- pass C: scatter edges into bucket-grouped order (LDS atomics only) ----
__global__ __launch_bounds__(256) void k_pC(const int* __restrict__ ei,
                                            const int* __restrict__ M,
                                            const int* __restrict__ bucketstart,
                                            uint* __restrict__ part) {
  __shared__ int lbase[NBUCK];
  __shared__ int lc[NBUCK];
  for (int k = threadIdx.x; k < NBUCK; k += 256) {
    lbase[k] = bucketstart[k] + M[blockIdx.x * NBUCK + k];
    lc[k] = 0;
  }
  __syncthreads();
  int lo = blockIdx.x * PCHUNK;
  int hi = lo + PCHUNK; if (hi > EPLUS) hi = EPLUS;
  for (int e = lo + threadIdx.x; e < hi; e += 256) {
    int src, dst;
    if (e < N_EDGES) { src = ei[e]; dst = ei[N_EDGES + e]; }
    else { src = dst = e - N_EDGES; }
    int b = dst >> 6;
    int p = lbase[b] + atomicAdd(&lc[b], 1);
    part[p] = (uint)src | ((uint)dst << 16);   // both ids < 2^16
  }
}

// ---- pass D: per-bucket fine CSR (64 dsts) via LDS counters + wave scan ----
__global__ __launch_bounds__(256) void k_pD(const uint* __restrict__ part,
                                            const int* __restrict__ bucketstart,
                                            int* __restrict__ rowstart,
                                            int* __restrict__ col) {
  __shared__ int dcnt[64], dstart[64], dc2[64];
  int b = blockIdx.x;
  int n0 = bucketstart[b], n1 = bucketstart[b + 1];
  int t = threadIdx.x;
  if (t < 64) { dcnt[t] = 0; dc2[t] = 0; }
  __syncthreads();
  for (int i = n0 + t; i < n1; i += 256)
    atomicAdd(&dcnt[(part[i] >> 16) & 63], 1);
  __syncthreads();
  if (t < 64) {
    int v = dcnt[t];
    int run = v;
    #pragma unroll
    for (int off = 1; off < 64; off <<= 1) {
      int u = __shfl_up(run, off);
      if (t >= off) run += u;
    }
    dstart[t] = run - v;   // exclusive within bucket
    int node = b * 64 + t;
    if (node < N_NODES) rowstart[node] = n0 + run - v;
  }
  if (b == NBUCK - 1 && t == 0) rowstart[N_NODES] = n1;  // = EPLUS
  __syncthreads();
  for (int i = n0 + t; i < n1; i += 256) {
    uint pr = part[i];
    int loc = (pr >> 16) & 63;
    int pos = n0 + dstart[loc] + atomicAdd(&dc2[loc], 1);
    col[pos] = (int)(pr & 0xffffu);
  }
}

// Y = X[N,128] @ W[128,128] via v_dot2_f32_f16: X/W tiles converted to f16-RNE
// pairs along K during staging; inner loop = 1 dot2 per 2 MACs (halves both
// math issue and LDS read count vs fp32 fma). B stored col-interleaved
// (pos=(c&7)*16+(c>>3)) so inner reads are 16-consecutive-word conflict-free.
// Epilogue: f16-pack h into hbu + es/ed per-head dots from fp32 accumulators.
__global__ __launch_bounds__(256) void k_gemm_fused(const float* __restrict__ X,
                                                    const float* __restrict__ W,
                                                    const float* __restrict__ asrc,
                                                    const float* __restrict__ adst,
                                                    uint* __restrict__ hbu,
                                                    float* __restrict__ es,
                                                    float* __restrict__ ed) {
  __shared__ uint As16[64][20];    // [row][kpair], pad 20 (2-way free)
  __shared__ uint Bs16[16][132];   // [kpair][col-interleaved]
  int tid = threadIdx.x;
  int r0 = blockIdx.x * 64;
  int tm = tid >> 4;   // 0..15 -> rows tm + 16*i, i<4
  int tn = tid & 15;   // 0..15 -> cols tn*8 .. +7  (all within head tn>>2)
  float acc[4][8];
  #pragma unroll
  for (int i = 0; i < 4; ++i)
    #pragma unroll
    for (int j = 0; j < 8; ++j) acc[i][j] = 0.f;

  for (int kc = 0; kc < 128; kc += 32) {
    // X tile 64x32 -> f16 pairs
    #pragma unroll
    for (int i = 0; i < 2; ++i) {
      int q = tid + 256 * i;
      int row = q >> 3;
      int kq = (q & 7) << 2;
      int gr = r0 + row;
      float4 v = make_float4(0.f, 0.f, 0.f, 0.f);
      if (gr < N_NODES) v = *(const float4*)&X[(size_t)gr * 128 + kc + kq];
      As16[row][(kq >> 1) + 0] = pkrn(v.x, v.y);
      As16[row][(kq >> 1) + 1] = pkrn(v.z, v.w);
    }
    // W tile 32x128 -> f16 pairs along k, col-interleaved
    {
      int kk = tid >> 4;            // 0..15 (k-pair)
      int c8 = (tid & 15) * 8;      // col base
      const float* wr0 = &W[(size_t)(kc + 2 * kk) * 128 + c8];
      float4 w0a = *(const float4*)wr0;
      float4 w0b = *(const float4*)(wr0 + 4);
      float4 w1a = *(const float4*)(wr0 + 128);
      float4 w1b = *(const float4*)(wr0 + 132);
      float w0v[8] = {w0a.x, w0a.y, w0a.z, w0a.w, w0b.x, w0b.y, w0b.z, w0b.w};
      float w1v[8] = {w1a.x, w1a.y, w1a.z, w1a.w, w1b.x, w1b.y, w1b.z, w1b.w};
      #pragma unroll
      for (int j = 0; j < 8; ++j) {
        int c = c8 + j;
        Bs16[kk][(c & 7) * 16 + (c >> 3)] = pkrn(w0v[j], w1v[j]);
      }
    }
    __syncthreads();
    #pragma unroll
    for (int kk = 0; kk < 16; ++kk) {
      uint a0 = As16[tm +  0][kk];
      uint a1 = As16[tm + 16][kk];
      uint a2 = As16[tm + 32][kk];
      uint a3 = As16[tm + 48][kk];
      uint b[8];
      #pragma unroll
      for (int j = 0; j < 8; ++j) b[j] = Bs16[kk][j * 16 + tn];
      #pragma unroll
      for (int j = 0; j < 8; ++j) {
        acc[0][j] = fdot2(a0, b[j], acc[0][j]);
        acc[1][j] = fdot2(a1, b[j], acc[1][j]);
        acc[2][j] = fdot2(a2, b[j], acc[2][j]);
        acc[3][j] = fdot2(a3, b[j], acc[3][j]);
      }
    }
    __syncthreads();
  }

  // epilogue: f16 pack (RNE) + per-head attention dots (fp32)
  float av_s[8], av_d[8];
  #pragma unroll
  for (int j = 0; j < 8; ++j) { av_s[j] = asrc[tn * 8 + j]; av_d[j] = adst[tn * 8 + j]; }
  int head = tn >> 2;
  #pragma unroll
  for (int i = 0; i < 4; ++i) {
    int row = r0 + tm + 16 * i;
    float ps = 0.f, pd = 0.f;
    uint us[8];
    #pragma unroll
    for (int j = 0; j < 8; ++j) {
      float v = acc[i][j];
      ps = fmaf(v, av_s[j], ps);
      pd = fmaf(v, av_d[j], pd);
      us[j] = (uint)__half_as_ushort(__float2half_rn(v));
    }
    // reduce over the 4 threads (same tm, same head): lanes base-aligned to 4
    ps += __shfl_xor(ps, 1); ps += __shfl_xor(ps, 2);
    pd += __shfl_xor(pd, 1); pd += __shfl_xor(pd, 2);
    if (row < N_NODES) {
      uint4 p;
      p.x = us[0] | (us[1] << 16);
      p.y = us[2] | (us[3] << 16);
      p.z = us[4] | (us[5] << 16);
      p.w = us[6] | (us[7] << 16);
      *(uint4*)&hbu[(size_t)row * 64 + tn * 4] = p;
      if ((tn & 3) == 0) {
        es[row * 4 + head] = ps;
        ed[row * 4 + head] = pd;
      }
    }
  }
}

// one wave per destination node. Phase A: lanes parallel over <=64 edges,
// exp-weights computed once per edge, stashed in LDS, denominator per-lane
// float4. Phase B: 16 lanes own 8 channels of one edge (uint4 = 8 f16);
// 16 edges per iteration = 4 independent dwordx4 gathers in flight (MLP);
// channel-pairs across edge pairs built with v_perm_b32 and multiplied with
// one v_dot2_f32_f16 per channel. Padded slots have w=0 (contribute nothing).
__global__ __launch_bounds__(256) void k_attn(const uint* __restrict__ hb,
                                              const float* __restrict__ es,
                                              const float* __restrict__ ed,
                                              const int* __restrict__ rowstart,
                                              const int* __restrict__ col,
                                              const float* __restrict__ bias,
                                              float* __restrict__ outp, int do_relu) {
  __shared__ float swv[4][4 * 68];   // [wave][head*68 + edge]
  __shared__ int   ssc[4][64];       // [wave][edge] = src<<8 (byte offset of h row)
  int lane = threadIdx.x & 63;
  int wv = threadIdx.x >> 6;
  int n = blockIdx.x * 4 + wv;
  if (n >= N_NODES) return;
  int s = rowstart[n], t = rowstart[n + 1];
  int sub = lane & 15;         // channel-group owner (8 channels)
  int esel = lane >> 4;        // edge-in-group selector (0..3)
  int head2 = sub >> 2;        // head of this lane's 8 channels
  float4 edv = *(const float4*)&ed[n * 4];
  const char* hbb = (const char*)hb + (uint)sub * 16u;   // lane's 16B slice
  const char* esb = (const char*)es;
  float* wv0 = swv[wv];
  int* sc0 = ssc[wv];

  float4 denv = make_float4(0.f, 0.f, 0.f, 0.f);
  float acc[8];
  #pragma unroll
  for (int j = 0; j < 8; ++j) acc[j] = 0.f;

  for (int base = s; base < t; base += 64) {
    int nthis = t - base; if (nthis > 64) nthis = 64;
    int npad = (nthis + 15) & ~15;
    // ---- phase A ----
    if (lane < nthis) {
      int sc = col[base + lane];
      float4 esv = *(const float4*)(esb + ((uint)sc << 4));
      float w0 = __expf(lrelu(esv.x + edv.x));
      float w1 = __expf(lrelu(esv.y + edv.y));
      float w2 = __expf(lrelu(esv.z + edv.z));
      float w3 = __expf(lrelu(esv.w + edv.w));
      denv.x += w0; denv.y += w1; denv.z += w2; denv.w += w3;
      wv0[0 * 68 + lane] = w0;
      wv0[1 * 68 + lane] = w1;
      wv0[2 * 68 + lane] = w2;
      wv0[3 * 68 + lane] = w3;
      sc0[lane] = sc << 8;
    } else if (lane < npad) {
      wv0[0 * 68 + lane] = 0.f;
      wv0[1 * 68 + lane] = 0.f;
      wv0[2 * 68 + lane] = 0.f;
      wv0[3 * 68 + lane] = 0.f;
      sc0[lane] = 0;
    }
    asm volatile("s_waitcnt lgkmcnt(0)" ::: "memory");
    // ---- phase B: 16 edges per iteration (4 gathers in flight) ----
    __builtin_amdgcn_s_setprio(1);
    for (int i = 0; i < npad; i += 16) {
      int e0 = i + esel, e1 = e0 + 4, e2 = e0 + 8, e3 = e0 + 12;
      float w0 = wv0[head2 * 68 + e0];
      float w1 = wv0[head2 * 68 + e1];
      float w2 = wv0[head2 * 68 + e2];
      float w3 = wv0[head2 * 68 + e3];
      int so0 = sc0[e0], so1 = sc0[e1], so2 = sc0[e2], so3 = sc0[e3];
      uint4 q0 = *(const uint4*)(hbb + (uint)so0);
      uint4 q1 = *(const uint4*)(hbb + (uint)so1);
      uint4 q2 = *(const uint4*)(hbb + (uint)so2);
      uint4 q3 = *(const uint4*)(hbb + (uint)so3);
      uint wa = pkrtz(w0, w1);
      uint wb = pkrtz(w2, w3);
      acc[0] = fdot2(__builtin_amdgcn_perm(q1.x, q0.x, 0x05040100u), wa, acc[0]);
      acc[1] = fdot2(__builtin_amdgcn_perm(q1.x, q0.x, 0x07060302u), wa, acc[1]);
      acc[2] = fdot2(__builtin_amdgcn_perm(q1.y, q0.y, 0x05040100u), wa, acc[2]);
      acc[3] = fdot2(__builtin_amdgcn_perm(q1.y, q0.y, 0x07060302u), wa, acc[3]);
      acc[4] = fdot2(__builtin_amdgcn_perm(q1.z, q0.z, 0x05040100u), wa, acc[4]);
      acc[5] = fdot2(__builtin_amdgcn_perm(q1.z, q0.z, 0x07060302u), wa, acc[5]);
      acc[6] = fdot2(__builtin_amdgcn_perm(q1.w, q0.w, 0x05040100u), wa, acc[6]);
      acc[7] = fdot2(__builtin_amdgcn_perm(q1.w, q0.w, 0x07060302u), wa, acc[7]);
      acc[0] = fdot2(__builtin_amdgcn_perm(q3.x, q2.x, 0x05040100u), wb, acc[0]);
      acc[1] = fdot2(__builtin_amdgcn_perm(q3.x, q2.x, 0x07060302u), wb, acc[1]);
      acc[2] = fdot2(__builtin_amdgcn_perm(q3.y, q2.y, 0x05040100u), wb, acc[2]);
      acc[3] = fdot2(__builtin_amdgcn_perm(q3.y, q2.y, 0x07060302u), wb, acc[3]);
      acc[4] = fdot2(__builtin_amdgcn_perm(q3.z, q2.z, 0x05040100u), wb, acc[4]);
      acc[5] = fdot2(__builtin_amdgcn_perm(q3.z, q2.z, 0x07060302u), wb, acc[5]);
      acc[6] = fdot2(__builtin_amdgcn_perm(q3.w, q2.w, 0x05040100u), wb, acc[6]);
      acc[7] = fdot2(__builtin_amdgcn_perm(q3.w, q2.w, 0x07060302u), wb, acc[7]);
    }
    __builtin_amdgcn_s_setprio(0);
  }
  // reduce partial sums across the 4 edge-selector groups
  #pragma unroll
  for (int j = 0; j < 8; ++j) {
    acc[j] += __shfl_xor(acc[j], 16);
    acc[j] += __shfl_xor(acc[j], 32);
  }
  // reduce denominator across lanes (once per node)
  #pragma unroll
  for (int off = 1; off < 64; off <<= 1) {
    denv.x += __shfl_xor(denv.x, off);
    denv.y += __shfl_xor(denv.y, off);
    denv.z += __shfl_xor(denv.z, off);
    denv.w += __shfl_xor(denv.w, off);
  }
  float den = (head2 & 2) ? ((head2 & 1) ? denv.w : denv.z)
                          : ((head2 & 1) ? denv.y : denv.x);
  float inv = 1.0f / (den + 1e-16f);
  if (lane < 32) {
    int half = lane >> 4;            // 0 or 1
    int c = sub * 8 + half * 4;
    float4 bb = *(const float4*)&bias[c];
    float o0 = acc[half * 4 + 0] * inv + bb.x;
    float o1 = acc[half * 4 + 1] * inv + bb.y;
    float o2 = acc[half * 4 + 2] * inv + bb.z;
    float o3 = acc[half * 4 + 3] * inv + bb.w;
    if (do_relu) {
      o0 = fmaxf(o0, 0.f); o1 = fmaxf(o1, 0.f);
      o2 = fmaxf(o2, 0.f); o3 = fmaxf(o3, 0.f);
    }
    *(float4*)&outp[(size_t)n * 128 + c] = make_float4(o0, o1, o2, o3);
  }
}

// one block per graph: mean-pool (binary search on sorted batch) + 128->4 classifier
__global__ __launch_bounds__(128) void k_poolcls(const float* __restrict__ out2,
                                                 const int* __restrict__ batch,
                                                 const float* __restrict__ wc,
                                                 const float* __restrict__ bc,
                                                 float* __restrict__ y) {
  int b = blockIdx.x;
  int c = threadIdx.x;
  int lo = 0, hi = N_NODES;
  while (lo < hi) { int mid = (lo + hi) >> 1; if (batch[mid] < b) lo = mid + 1; else hi = mid; }
  int s = lo;
  lo = s; hi = N_NODES;
  while (lo < hi) { int mid = (lo + hi) >> 1; if (batch[mid] < b + 1) lo = mid + 1; else hi = mid; }
  int e = lo;
  float acc0 = 0.f, acc1 = 0.f, acc2 = 0.f, acc3 = 0.f;
  int nidx = s;
  for (; nidx + 4 <= e; nidx += 4) {
    acc0 += out2[(size_t)nidx * 128 + c];
    acc1 += out2[(size_t)(nidx + 1) * 128 + c];
    acc2 += out2[(size_t)(nidx + 2) * 128 + c];
    acc3 += out2[(size_t)(nidx + 3) * 128 + c];
  }
  for (; nidx < e; ++nidx) acc0 += out2[(size_t)nidx * 128 + c];
  float acc = (acc0 + acc1) + (acc2 + acc3);
  float cnt = (float)(e - s);
  float pooled = acc / fmaxf(cnt, 1.0f);
  float4 wrow = *(const float4*)&wc[c * 4];
  float wj[4] = {wrow.x, wrow.y, wrow.z, wrow.w};
  __shared__ float red[128];
  #pragma unroll
  for (int j = 0; j < 4; ++j) {
    red[c] = pooled * wj[j];
    __syncthreads();
    for (int off = 64; off > 0; off >>= 1) {
      if (c < off) red[c] += red[c + off];
      __syncthreads();
    }
    if (c == 0) y[b * 4 + j] = red[0] + bc[j];
    __syncthreads();
  }
}

extern "C" void kernel_launch(void* const* d_in, const int* in_sizes, int n_in,
                              void* d_out, int out_size, void* d_ws, size_t ws_size,
                              hipStream_t stream) {
  const float* x    = (const float*)d_in[0];
  const int*   ei   = (const int*)d_in[1];
  const int*   batch= (const int*)d_in[2];
  const float* w1   = (const float*)d_in[3];
  const float* as1  = (const float*)d_in[4];
  const float* ad1  = (const float*)d_in[5];
  const float* b1   = (const float*)d_in[6];
  const float* w2   = (const float*)d_in[7];
  const float* as2  = (const float*)d_in[8];
  const float* ad2  = (const float*)d_in[9];
  const float* b2   = (const float*)d_in[10];
  const float* wc   = (const float*)d_in[11];
  const float* bc   = (const float*)d_in[12];
  float* y = (float*)d_out;

  char* ws = (char*)d_ws;
  size_t o = 0;
  auto take = [&](size_t bytes) { void* p = ws + o; o = (o + bytes + 255) & ~(size_t)255; return p; };
  uint*  hbu      = (uint*)take((size_t)N_NODES * 64 * 4);        // f16 h, packed 2/word
  float* obuf     = (float*)take((size_t)N_NODES * HCH * 4);      // fp32 layer outputs
  float* es       = (float*)take((size_t)N_NODES * 4 * 4);
  float* ed       = (float*)take((size_t)N_NODES * 4 * 4);
  int*   M        = (int*)take((size_t)NSB * NBUCK * 4);          // per-block bucket hist/prefix
  int*   tot      = (int*)take((size_t)NBUCK * 4);
  int*   bstart   = (int*)take((size_t)(NBUCK + 1) * 4);
  uint*  part     = (uint*)take((size_t)EPLUS * 4);               // bucket-grouped packed edges
  int*   rowstart = (int*)take((size_t)(N_NODES + 1) * 4);
  int*   col      = (int*)take((size_t)EPLUS * 4);

  const int GW = N_NODES / 4;               // 12500 wave-per-node
  const int GG = (N_NODES + 63) / 64;       // 782 gemm blocks

  // ---- CSR build (no global returning atomics; scan parallel across CUs) ----
  k_pA<<<NSB, 256, 0, stream>>>(ei, M);
  k_pB1<<<NBUCK, 256, 0, stream>>>(M, tot);
  k_pB2<<<1, 1024, 0, stream>>>(tot, bstart);
  k_pC<<<NSB, 256, 0, stream>>>(ei, M, bstart, part);
  k_pD<<<NBUCK, 256, 0, stream>>>(part, bstart, rowstart, col);

  // ---- layer 1 ----
  k_gemm_fused<<<GG, 256, 0, stream>>>(x, w1, as1, ad1, hbu, es, ed);
  k_attn<<<GW, 256, 0, stream>>>(hbu, es, ed, rowstart, col, b1, obuf, 1);

  // ---- layer 2 ----
  k_gemm_fused<<<GG, 256, 0, stream>>>(obuf, w2, as2, ad2, hbu, es, ed);
  k_attn<<<GW, 256, 0, stream>>>(hbu, es, ed, rowstart, col, b2, obuf, 0);

  // ---- pool + classifier ----
  k_poolcls<<<NB, 128, 0, stream>>>(obuf, batch, wc, bc, y);
}

// Round 16
// 235.065 us; speedup vs baseline: 1.3502x; 1.0188x over previous
//
#include <hip/hip_runtime.h>
#include <hip/hip_fp16.h>

#define N_NODES 50000
#define N_EDGES 1600000
#define EPLUS   1650000   // edges + self loops
#define HCH 128           // hidden channels (H*C)
#define NB 512            // graphs
#define NCLS 4
#define NBUCK 782         // ceil(N_NODES/64); bucket = dst>>6
#define NSB 256           // scatter blocks for passes A/C
#define PCHUNK 6446       // ceil(EPLUS/NSB)

typedef unsigned int uint;

__device__ __forceinline__ float lrelu(float v) { return v > 0.f ? v : 0.2f * v; }

// D = a.lo*b.lo + a.hi*b.hi + c  (f16 pairs, f32 accumulate)
__device__ __forceinline__ float fdot2(uint a, uint b, float c) {
  asm("v_dot2_f32_f16 %0, %1, %2, %0" : "+v"(c) : "v"(a), "v"(b));
  return c;
}

// pack two f32 -> two f16 (RTZ) in one VGPR
__device__ __forceinline__ uint pkrtz(float a, float b) {
  auto v = __builtin_amdgcn_cvt_pkrtz(a, b);
  uint r;
  __builtin_memcpy(&r, &v, 4);
  return r;
}

// pack two f32 -> two f16 (RNE)
__device__ __forceinline__ uint pkrn(float a, float b) {
  return (uint)__half_as_ushort(__float2half_rn(a)) |
         ((uint)__half_as_ushort(__float2half_rn(b)) << 16);
}

// ---- pass A: per-block bucket histogram (LDS atomics only) ----
__global__ __launch_bounds__(256) void k_pA(const int* __restrict__ ei,
                                            int* __restrict__ M) {
  __shared__ int lh[NBUCK];
  for (int k = threadIdx.x; k < NBUCK; k += 256) lh[k] = 0;
  __syncthreads();
  int lo = blockIdx.x * PCHUNK;
  int hi = lo + PCHUNK; if (hi > EPLUS) hi = EPLUS;
  for (int e = lo + threadIdx.x; e < hi; e += 256) {
    int dst = (e < N_EDGES) ? ei[N_EDGES + e] : (e - N_EDGES);
    atomicAdd(&lh[dst >> 6], 1);
  }
  __syncthreads();
  for (int k = threadIdx.x; k < NBUCK; k += 256)
    M[blockIdx.x * NBUCK + k] = lh[k];
}

// ---- pass B1: per-bucket scan over the NSB block-counts (one block/bucket) ----
__global__ __launch_bounds__(256) void k_pB1(int* __restrict__ M,
                                             int* __restrict__ tot) {
  __shared__ int sm[256];
  int k = blockIdx.x;            // bucket
  int t = threadIdx.x;           // scatter-block index
  int v = M[t * NBUCK + k];
  sm[t] = v;
  __syncthreads();
  for (int off = 1; off < 256; off <<= 1) {
    int u = (t >= off) ? sm[t - off] : 0;
    __syncthreads();
    sm[t] += u;
    __syncthreads();
  }
  M[t * NBUCK + k] = sm[t] - v;  // within-bucket, over-blocks exclusive prefix
  if (t == 255) tot[k] = sm[255];
}

// ---- pass B2: bucket exclusive scan over 782 totals (1 small block-scan) ----
__global__ __launch_bounds__(1024) void k_pB2(const int* __restrict__ tot,
                                              int* __restrict__ bucketstart) {
  __shared__ int sm[1024];
  int k = threadIdx.x;
  int v = (k < NBUCK) ? tot[k] : 0;
  sm[k] = v;
  __syncthreads();
  for (int off = 1; off < 1024; off <<= 1) {
    int u = (k >= off) ? sm[k - off] : 0;
    __syncthreads();
    sm[k] += u;
    __syncthreads();
  }
  if (k < NBUCK) {
    bucketstart[k] = sm[k] - v;                      // exclusive
    if (k == NBUCK - 1) bucketstart[NBUCK] = sm[k];  // = EPLUS
  }
}

// ---- pass C: scatter edges into bucket-grouped order (LDS atomics only) ----
__global__ __launch_bounds__(256) void k_pC(const int* __restrict__ ei,
                                            const int* __restrict__ M,
                                            const int* __restrict__ bucketstart,
                                            uint* __restrict__ part) {
  __shared__ int lbase[NBUCK];
  __shared__ int lc[NBUCK];
  for (int k = threadIdx.x; k < NBUCK; k += 256) {
    lbase[k] = bucketstart[k] + M[blockIdx.x * NBUCK + k];
    lc[k] = 0;
  }
  __syncthreads();
  int lo = blockIdx.x * PCHUNK;
  int hi = lo + PCHUNK; if (hi > EPLUS) hi = EPLUS;
  for (int e = lo + threadIdx.x; e < hi; e += 256) {
    int src, dst;
    if (e < N_EDGES) { src = ei[e]; dst = ei[N_EDGES + e]; }
    else { src = dst = e - N_EDGES; }
    int b = dst >> 6;
    int p = lbase[b] + atomicAdd(&lc[b], 1);
    part[p] = (uint)src | ((uint)dst << 16);   // both ids < 2^16
  }
}

// ---- pass D: per-bucket fine CSR (64 dsts) via LDS counters + wave scan ----
__global__ __launch_bounds__(256) void k_pD(const uint* __restrict__ part,
                                            const int* __restrict__ bucketstart,
                                            int* __restrict__ rowstart,
                                            int* __restrict__ col) {
  __shared__ int dcnt[64], dstart[64], dc2[64];
  int b = blockIdx.x;
  int n0 = bucketstart[b], n1 = bucketstart[b + 1];
  int t = threadIdx.x;
  if (t < 64) { dcnt[t] = 0; dc2[t] = 0; }
  __syncthreads();
  for (int i = n0 + t; i < n1; i += 256)
    atomicAdd(&dcnt[(part[i] >> 16) & 63], 1);
  __syncthreads();
  if (t < 64) {
    int v = dcnt[t];
    int run = v;
    #pragma unroll
    for (int off = 1; off < 64; off <<= 1) {
      int u = __shfl_up(run, off);
      if (t >= off) run += u;
    }
    dstart[t] = run - v;   // exclusive within bucket
    int node = b * 64 + t;
    if (node < N_NODES) rowstart[node] = n0 + run - v;
  }
  if (b == NBUCK - 1 && t == 0) rowstart[N_NODES] = n1;  // = EPLUS
  __syncthreads();
  for (int i = n0 + t; i < n1; i += 256) {
    uint pr = part[i];
    int loc = (pr >> 16) & 63;
    int pos = n0 + dstart[loc] + atomicAdd(&dc2[loc], 1);
    col[pos] = (int)(pr & 0xffffu);
  }
}

// Y = X @ W via v_dot2_f32_f16. XF16=1: X already f16-packed (layer-1 output)
// -> staging is a straight uint4 copy. Inner loop reads A and B as b64 pairs
// along k (halves LDS read instructions). Bs2 layout [colmap][kpair] stride 18:
// writes <=2-way conflict (free), reads conflict-free broadcast.
// Epilogue: f16-pack h into hbu + es/ed per-head dots from fp32 accumulators.
template<int XF16>
__global__ __launch_bounds__(256) void k_gemm_fused(const float* __restrict__ X,
                                                    const uint* __restrict__ X16,
                                                    const float* __restrict__ W,
                                                    const float* __restrict__ asrc,
                                                    const float* __restrict__ adst,
                                                    uint* __restrict__ hbu,
                                                    float* __restrict__ es,
                                                    float* __restrict__ ed) {
  __shared__ uint As16[64][20];    // [row][kpair], stride 20
  __shared__ uint Bs2[128][18];    // [(c&7)*16+(c>>3)][kpair], stride 18
  int tid = threadIdx.x;
  int r0 = blockIdx.x * 64;
  int tm = tid >> 4;   // 0..15 -> rows tm + 16*i, i<4
  int tn = tid & 15;   // 0..15 -> cols tn*8 .. +7  (all within head tn>>2)
  float acc[4][8];
  #pragma unroll
  for (int i = 0; i < 4; ++i)
    #pragma unroll
    for (int j = 0; j < 8; ++j) acc[i][j] = 0.f;

  for (int kc = 0; kc < 128; kc += 32) {
    // ---- X tile 64x32 -> f16 k-pairs ----
    if (XF16) {
      int row = tid >> 2;           // 0..63
      int kq4 = (tid & 3) * 4;      // uint offset within the 16-uint k-block
      int gr = r0 + row;
      uint4 v = make_uint4(0u, 0u, 0u, 0u);
      if (gr < N_NODES) v = *(const uint4*)&X16[(size_t)gr * 64 + (kc >> 1) + kq4];
      *(uint4*)&As16[row][kq4] = v;
    } else {
      #pragma unroll
      for (int i = 0; i < 2; ++i) {
        int q = tid + 256 * i;
        int row = q >> 3;
        int kq = (q & 7) << 2;
        int gr = r0 + row;
        float4 v = make_float4(0.f, 0.f, 0.f, 0.f);
        if (gr < N_NODES) v = *(const float4*)&X[(size_t)gr * 128 + kc + kq];
        As16[row][(kq >> 1) + 0] = pkrn(v.x, v.y);
        As16[row][(kq >> 1) + 1] = pkrn(v.z, v.w);
      }
    }
    // ---- W tile 32x128 -> f16 k-pairs, [colmap][kpair] ----
    {
      int kk = tid >> 4;            // 0..15 (k-pair)
      int c8 = (tid & 15) * 8;      // col base
      const float* wr0 = &W[(size_t)(kc + 2 * kk) * 128 + c8];
      float4 w0a = *(const float4*)wr0;
      float4 w0b = *(const float4*)(wr0 + 4);
      float4 w1a = *(const float4*)(wr0 + 128);
      float4 w1b = *(const float4*)(wr0 + 132);
      float w0v[8] = {w0a.x, w0a.y, w0a.z, w0a.w, w0b.x, w0b.y, w0b.z, w0b.w};
      float w1v[8] = {w1a.x, w1a.y, w1a.z, w1a.w, w1b.x, w1b.y, w1b.z, w1b.w};
      #pragma unroll
      for (int j = 0; j < 8; ++j)
        Bs2[j * 16 + (tid & 15)][kk] = pkrn(w0v[j], w1v[j]);
    }
    __syncthreads();
    #pragma unroll
    for (int kk = 0; kk < 16; kk += 2) {
      uint2 a0 = *(const uint2*)&As16[tm +  0][kk];
      uint2 a1 = *(const uint2*)&As16[tm + 16][kk];
      uint2 a2 = *(const uint2*)&As16[tm + 32][kk];
      uint2 a3 = *(const uint2*)&As16[tm + 48][kk];
      #pragma unroll
      for (int j = 0; j < 8; ++j) {
        uint2 b = *(const uint2*)&Bs2[j * 16 + tn][kk];
        acc[0][j] = fdot2(a0.x, b.x, acc[0][j]);
        acc[0][j] = fdot2(a0.y, b.y, acc[0][j]);
        acc[1][j] = fdot2(a1.x, b.x, acc[1][j]);
        acc[1][j] = fdot2(a1.y, b.y, acc[1][j]);
        acc[2][j] = fdot2(a2.x, b.x, acc[2][j]);
        acc[2][j] = fdot2(a2.y, b.y, acc[2][j]);
        acc[3][j] = fdot2(a3.x, b.x, acc[3][j]);
        acc[3][j] = fdot2(a3.y, b.y, acc[3][j]);
      }
    }
    __syncthreads();
  }

  // epilogue: f16 pack (RNE) + per-head attention dots (fp32)
  float av_s[8], av_d[8];
  #pragma unroll
  for (int j = 0; j < 8; ++j) { av_s[j] = asrc[tn * 8 + j]; av_d[j] = adst[tn * 8 + j]; }
  int head = tn >> 2;
  #pragma unroll
  for (int i = 0; i < 4; ++i) {
    int row = r0 + tm + 16 * i;
    float ps = 0.f, pd = 0.f;
    uint us[8];
    #pragma unroll
    for (int j = 0; j < 8; ++j) {
      float v = acc[i][j];
      ps = fmaf(v, av_s[j], ps);
      pd = fmaf(v, av_d[j], pd);
      us[j] = (uint)__half_as_ushort(__float2half_rn(v));
    }
    // reduce over the 4 threads (same tm, same head): lanes base-aligned to 4
    ps += __shfl_xor(ps, 1); ps += __shfl_xor(ps, 2);
    pd += __shfl_xor(pd, 1); pd += __shfl_xor(pd, 2);
    if (row < N_NODES) {
      uint4 p;
      p.x = us[0] | (us[1] << 16);
      p.y = us[2] | (us[3] << 16);
      p.z = us[4] | (us[5] << 16);
      p.w = us[6] | (us[7] << 16);
      *(uint4*)&hbu[(size_t)row * 64 + tn * 4] = p;
      if ((tn & 3) == 0) {
        es[row * 4 + head] = ps;
        ed[row * 4 + head] = pd;
      }
    }
  }
}

// one wave per destination node. Phase A: lanes parallel over <=64 edges,
// exp-weights computed once per edge, stashed in LDS, denominator per-lane
// float4. Phase B: 16 lanes own 8 channels of one edge (uint4 = 8 f16);
// 16 edges per iteration = 4 independent dwordx4 gathers in flight (MLP);
// channel-pairs across edge pairs built with v_perm_b32 and multiplied with
// one v_dot2_f32_f16 per channel. Padded slots have w=0 (contribute nothing).
// wf16=1: write f16-packed output (layer-1 intermediate; bit-identical to the
// fp32-store + staging-RNE path it replaces, halves write+reread bytes).
__global__ __launch_bounds__(256) void k_attn(const uint* __restrict__ hb,
                                              const float* __restrict__ es,
                                              const float* __restrict__ ed,
                                              const int* __restrict__ rowstart,
                                              const int* __restrict__ col,
                                              const float* __restrict__ bias,
                                              float* __restrict__ outp,
                                              uint* __restrict__ out16,
                                              int do_relu, int wf16) {
  __shared__ float swv[4][4 * 68];   // [wave][head*68 + edge]
  __shared__ int   ssc[4][64];       // [wave][edge] = src<<8 (byte offset of h row)
  int lane = threadIdx.x & 63;
  int wv = threadIdx.x >> 6;
  int n = blockIdx.x * 4 + wv;
  if (n >= N_NODES) return;
  int s = rowstart[n], t = rowstart[n + 1];
  int sub = lane & 15;         // channel-group owner (8 channels)
  int esel = lane >> 4;        // edge-in-group selector (0..3)
  int head2 = sub >> 2;        // head of this lane's 8 channels
  float4 edv = *(const float4*)&ed[n * 4];
  const char* hbb = (const char*)hb + (uint)sub * 16u;   // lane's 16B slice
  const char* esb = (const char*)es;
  float* wv0 = swv[wv];
  int* sc0 = ssc[wv];

  float4 denv = make_float4(0.f, 0.f, 0.f, 0.f);
  float acc[8];
  #pragma unroll
  for (int j = 0; j < 8; ++j) acc[j] = 0.f;

  for (int base = s; base < t; base += 64) {
    int nthis = t - base; if (nthis > 64) nthis = 64;
    int npad = (nthis + 15) & ~15;
    // ---- phase A ----
    if (lane < nthis) {
      int sc = col[base + lane];
      float4 esv = *(const float4*)(esb + ((uint)sc << 4));
      float w0 = __expf(lrelu(esv.x + edv.x));
      float w1 = __expf(lrelu(esv.y + edv.y));
      float w2 = __expf(lrelu(esv.z + edv.z));
      float w3 = __expf(lrelu(esv.w + edv.w));
      denv.x += w0; denv.y += w1; denv.z += w2; denv.w += w3;
      wv0[0 * 68 + lane] = w0;
      wv0[1 * 68 + lane] = w1;
      wv0[2 * 68 + lane] = w2;
      wv0[3 * 68 + lane] = w3;
      sc0[lane] = sc << 8;
    } else if (lane < npad) {
      wv0[0 * 68 + lane] = 0.f;
      wv0[1 * 68 + lane] = 0.f;
      wv0[2 * 68 + lane] = 0.f;
      wv0[3 * 68 + lane] = 0.f;
      sc0[lane] = 0;
    }
    asm volatile("s_waitcnt lgkmcnt(0)" ::: "memory");
    // ---- phase B: 16 edges per iteration (4 gathers in flight) ----
    __builtin_amdgcn_s_setprio(1);
    for (int i = 0; i < npad; i += 16) {
      int e0 = i + esel, e1 = e0 + 4, e2 = e0 + 8, e3 = e0 + 12;
      float w0 = wv0[head2 * 68 + e0];
      float w1 = wv0[head2 * 68 + e1];
      float w2 = wv0[head2 * 68 + e2];
      float w3 = wv0[head2 * 68 + e3];
      int so0 = sc0[e0], so1 = sc0[e1], so2 = sc0[e2], so3 = sc0[e3];
      uint4 q0 = *(const uint4*)(hbb + (uint)so0);
      uint4 q1 = *(const uint4*)(hbb + (uint)so1);
      uint4 q2 = *(const uint4*)(hbb + (uint)so2);
      uint4 q3 = *(const uint4*)(hbb + (uint)so3);
      uint wa = pkrtz(w0, w1);
      uint wb = pkrtz(w2, w3);
      acc[0] = fdot2(__builtin_amdgcn_perm(q1.x, q0.x, 0x05040100u), wa, acc[0]);
      acc[1] = fdot2(__builtin_amdgcn_perm(q1.x, q0.x, 0x07060302u), wa, acc[1]);
      acc[2] = fdot2(__builtin_amdgcn_perm(q1.y, q0.y, 0x05040100u), wa, acc[2]);
      acc[3] = fdot2(__builtin_amdgcn_perm(q1.y, q0.y, 0x07060302u), wa, acc[3]);
      acc[4] = fdot2(__builtin_amdgcn_perm(q1.z, q0.z, 0x05040100u), wa, acc[4]);
      acc[5] = fdot2(__builtin_amdgcn_perm(q1.z, q0.z, 0x07060302u), wa, acc[5]);
      acc[6] = fdot2(__builtin_amdgcn_perm(q1.w, q0.w, 0x05040100u), wa, acc[6]);
      acc[7] = fdot2(__builtin_amdgcn_perm(q1.w, q0.w, 0x07060302u), wa, acc[7]);
      acc[0] = fdot2(__builtin_amdgcn_perm(q3.x, q2.x, 0x05040100u), wb, acc[0]);
      acc[1] = fdot2(__builtin_amdgcn_perm(q3.x, q2.x, 0x07060302u), wb, acc[1]);
      acc[2] = fdot2(__builtin_amdgcn_perm(q3.y, q2.y, 0x05040100u), wb, acc[2]);
      acc[3] = fdot2(__builtin_amdgcn_perm(q3.y, q2.y, 0x07060302u), wb, acc[3]);
      acc[4] = fdot2(__builtin_amdgcn_perm(q3.z, q2.z, 0x05040100u), wb, acc[4]);
      acc[5] = fdot2(__builtin_amdgcn_perm(q3.z, q2.z, 0x07060302u), wb, acc[5]);
      acc[6] = fdot2(__builtin_amdgcn_perm(q3.w, q2.w, 0x05040100u), wb, acc[6]);
      acc[7] = fdot2(__builtin_amdgcn_perm(q3.w, q2.w, 0x07060302u), wb, acc[7]);
    }
    __builtin_amdgcn_s_setprio(0);
  }
  // reduce partial sums across the 4 edge-selector groups
  #pragma unroll
  for (int j = 0; j < 8; ++j) {
    acc[j] += __shfl_xor(acc[j], 16);
    acc[j] += __shfl_xor(acc[j], 32);
  }
  // reduce denominator across lanes (once per node)
  #pragma unroll
  for (int off = 1; off < 64; off <<= 1) {
    denv.x += __shfl_xor(denv.x, off);
    denv.y += __shfl_xor(denv.y, off);
    denv.z += __shfl_xor(denv.z, off);
    denv.w += __shfl_xor(denv.w, off);
  }
  float den = (head2 & 2) ? ((head2 & 1) ? denv.w : denv.z)
                          : ((head2 & 1) ? denv.y : denv.x);
  float inv = 1.0f / (den + 1e-16f);
  if (lane < 32) {
    int half = lane >> 4;            // 0 or 1
    int c = sub * 8 + half * 4;
    float4 bb = *(const float4*)&bias[c];
    float o0 = acc[half * 4 + 0] * inv + bb.x;
    float o1 = acc[half * 4 + 1] * inv + bb.y;
    float o2 = acc[half * 4 + 2] * inv + bb.z;
    float o3 = acc[half * 4 + 3] * inv + bb.w;
    if (do_relu) {
      o0 = fmaxf(o0, 0.f); o1 = fmaxf(o1, 0.f);
      o2 = fmaxf(o2, 0.f); o3 = fmaxf(o3, 0.f);
    }
    if (wf16) {
      uint2 p2;
      p2.x = pkrn(o0, o1);
      p2.y = pkrn(o2, o3);
      *(uint2*)&out16[(size_t)n * 64 + sub * 4 + half * 2] = p2;
    } else {
      *(float4*)&outp[(size_t)n * 128 + c] = make_float4(o0, o1, o2, o3);
    }
  }
}

// one block per graph: mean-pool (binary search on sorted batch) + 128->4 classifier
__global__ __launch_bounds__(128) void k_poolcls(const float* __restrict__ out2,
                                                 const int* __restrict__ batch,
                                                 const float* __restrict__ wc,
                                                 const float* __restrict__ bc,
                                                 float* __restrict__ y) {
  int b = blockIdx.x;
  int c = threadIdx.x;
  int lo = 0, hi = N_NODES;
  while (lo < hi) { int mid = (lo + hi) >> 1; if (batch[mid] < b) lo = mid + 1; else hi = mid; }
  int s = lo;
  lo = s; hi = N_NODES;
  while (lo < hi) { int mid = (lo + hi) >> 1; if (batch[mid] < b + 1) lo = mid + 1; else hi = mid; }
  int e = lo;
  float acc0 = 0.f, acc1 = 0.f, acc2 = 0.f, acc3 = 0.f;
  int nidx = s;
  for (; nidx + 4 <= e; nidx += 4) {
    acc0 += out2[(size_t)nidx * 128 + c];
    acc1 += out2[(size_t)(nidx + 1) * 128 + c];
    acc2 += out2[(size_t)(nidx + 2) * 128 + c];
    acc3 += out2[(size_t)(nidx + 3) * 128 + c];
  }
  for (; nidx < e; ++nidx) acc0 += out2[(size_t)nidx * 128 + c];
  float acc = (acc0 + acc1) + (acc2 + acc3);
  float cnt = (float)(e - s);
  float pooled = acc / fmaxf(cnt, 1.0f);
  float4 wrow = *(const float4*)&wc[c * 4];
  float wj[4] = {wrow.x, wrow.y, wrow.z, wrow.w};
  __shared__ float red[128];
  #pragma unroll
  for (int j = 0; j < 4; ++j) {
    red[c] = pooled * wj[j];
    __syncthreads();
    for (int off = 64; off > 0; off >>= 1) {
      if (c < off) red[c] += red[c + off];
      __syncthreads();
    }
    if (c == 0) y[b * 4 + j] = red[0] + bc[j];
    __syncthreads();
  }
}

extern "C" void kernel_launch(void* const* d_in, const int* in_sizes, int n_in,
                              void* d_out, int out_size, void* d_ws, size_t ws_size,
                              hipStream_t stream) {
  const float* x    = (const float*)d_in[0];
  const int*   ei   = (const int*)d_in[1];
  const int*   batch= (const int*)d_in[2];
  const float* w1   = (const float*)d_in[3];
  const float* as1  = (const float*)d_in[4];
  const float* ad1  = (const float*)d_in[5];
  const float* b1   = (const float*)d_in[6];
  const float* w2   = (const float*)d_in[7];
  const float* as2  = (const float*)d_in[8];
  const float* ad2  = (const float*)d_in[9];
  const float* b2   = (const float*)d_in[10];
  const float* wc   = (const float*)d_in[11];
  const float* bc   = (const float*)d_in[12];
  float* y = (float*)d_out;

  char* ws = (char*)d_ws;
  size_t o = 0;
  auto take = [&](size_t bytes) { void* p = ws + o; o = (o + bytes + 255) & ~(size_t)255; return p; };
  uint*  hbu      = (uint*)take((size_t)N_NODES * 64 * 4);        // f16 h, packed 2/word
  uint*  h1u      = (uint*)take((size_t)N_NODES * 64 * 4);        // f16 layer-1 output
  float* obuf     = (float*)take((size_t)N_NODES * HCH * 4);      // fp32 layer-2 output
  float* es       = (float*)take((size_t)N_NODES * 4 * 4);
  float* ed       = (float*)take((size_t)N_NODES * 4 * 4);
  int*   M        = (int*)take((size_t)NSB * NBUCK * 4);          // per-block bucket hist/prefix
  int*   tot      = (int*)take((size_t)NBUCK * 4);
  int*   bstart   = (int*)take((size_t)(NBUCK + 1) * 4);
  uint*  part     = (uint*)take((size_t)EPLUS * 4);               // bucket-grouped packed edges
  int*   rowstart = (int*)take((size_t)(N_NODES + 1) * 4);
  int*   col      = (int*)take((size_t)EPLUS * 4);

  const int GW = N_NODES / 4;               // 12500 wave-per-node
  const int GG = (N_NODES + 63) / 64;       // 782 gemm blocks

  // ---- CSR build (no global returning atomics; scan parallel across CUs) ----
  k_pA<<<NSB, 256, 0, stream>>>(ei, M);
  k_pB1<<<NBUCK, 256, 0, stream>>>(M, tot);
  k_pB2<<<1, 1024, 0, stream>>>(tot, bstart);
  k_pC<<<NSB, 256, 0, stream>>>(ei, M, bstart, part);
  k_pD<<<NBUCK, 256, 0, stream>>>(part, bstart, rowstart, col);

  // ---- layer 1 ----
  k_gemm_fused<0><<<GG, 256, 0, stream>>>(x, nullptr, w1, as1, ad1, hbu, es, ed);
  k_attn<<<GW, 256, 0, stream>>>(hbu, es, ed, rowstart, col, b1, obuf, h1u, 1, 1);

  // ---- layer 2 (X from f16 layer-1 output; bit-identical to fp32+re-round) ----
  k_gemm_fused<1><<<GG, 256, 0, stream>>>(nullptr, h1u, w2, as2, ad2, hbu, es, ed);
  k_attn<<<GW, 256, 0, stream>>>(hbu, es, ed, rowstart, col, b2, obuf, h1u, 0, 0);

  // ---- pool + classifier ----
  k_poolcls<<<NB, 128, 0, stream>>>(obuf, batch, wc, bc, y);
}

// Round 17
// 218.825 us; speedup vs baseline: 1.4504x; 1.0742x over previous
//
#include <hip/hip_runtime.h>
#include <hip/hip_fp16.h>

#define N_NODES 50000
#define N_EDGES 1600000
#define EPLUS   1650000   // edges + self loops
#define HCH 128           // hidden channels (H*C)
#define NB 512            // graphs
#define NCLS 4
#define NBUCK 782         // ceil(N_NODES/64); bucket = dst>>6
#define NSB 256           // scatter blocks for passes A/C
#define PCHUNK 6446       // ceil(EPLUS/NSB)

typedef unsigned int uint;
typedef __attribute__((ext_vector_type(8))) _Float16 f16x8;
typedef __attribute__((ext_vector_type(4))) float f32x4;

__device__ __forceinline__ float lrelu(float v) { return v > 0.f ? v : 0.2f * v; }

// D = a.lo*b.lo + a.hi*b.hi + c  (f16 pairs, f32 accumulate)
__device__ __forceinline__ float fdot2(uint a, uint b, float c) {
  asm("v_dot2_f32_f16 %0, %1, %2, %0" : "+v"(c) : "v"(a), "v"(b));
  return c;
}

// pack two f32 -> two f16 (RTZ) in one VGPR
__device__ __forceinline__ uint pkrtz(float a, float b) {
  auto v = __builtin_amdgcn_cvt_pkrtz(a, b);
  uint r;
  __builtin_memcpy(&r, &v, 4);
  return r;
}

// pack two f32 -> two f16 (RNE)
__device__ __forceinline__ uint pkrn(float a, float b) {
  return (uint)__half_as_ushort(__float2half_rn(a)) |
         ((uint)__half_as_ushort(__float2half_rn(b)) << 16);
}

// ---- pass A: per-block bucket histogram (LDS atomics only) ----
__global__ __launch_bounds__(256) void k_pA(const int* __restrict__ ei,
                                            int* __restrict__ M) {
  __shared__ int lh[NBUCK];
  for (int k = threadIdx.x; k < NBUCK; k += 256) lh[k] = 0;
  __syncthreads();
  int lo = blockIdx.x * PCHUNK;
  int hi = lo + PCHUNK; if (hi > EPLUS) hi = EPLUS;
  for (int e = lo + threadIdx.x; e < hi; e += 256) {
    int dst = (e < N_EDGES) ? ei[N_EDGES + e] : (e - N_EDGES);
    atomicAdd(&lh[dst >> 6], 1);
  }
  __syncthreads();
  for (int k = threadIdx.x; k < NBUCK; k += 256)
    M[blockIdx.x * NBUCK + k] = lh[k];
}

// ---- pass B1: per-bucket scan over the NSB block-counts (one block/bucket) ----
__global__ __launch_bounds__(256) void k_pB1(int* __restrict__ M,
                                             int* __restrict__ tot) {
  __shared__ int sm[256];
  int k = blockIdx.x;            // bucket
  int t = threadIdx.x;           // scatter-block index
  int v = M[t * NBUCK + k];
  sm[t] = v;
  __syncthreads();
  for (int off = 1; off < 256; off <<= 1) {
    int u = (t >= off) ? sm[t - off] : 0;
    __syncthreads();
    sm[t] += u;
    __syncthreads();
  }
  M[t * NBUCK + k] = sm[t] - v;  // within-bucket, over-blocks exclusive prefix
  if (t == 255) tot[k] = sm[255];
}

// ---- pass B2: bucket exclusive scan over 782 totals (1 small block-scan) ----
__global__ __launch_bounds__(1024) void k_pB2(const int* __restrict__ tot,
                                              int* __restrict__ bucketstart) {
  __shared__ int sm[1024];
  int k = threadIdx.x;
  int v = (k < NBUCK) ? tot[k] : 0;
  sm[k] = v;
  __syncthreads();
  for (int off = 1; off < 1024; off <<= 1) {
    int u = (k >= off) ? sm[k - off] : 0;
    __syncthreads();
    sm[k] += u;
    __syncthreads();
  }
  if (k < NBUCK) {
    bucketstart[k] = sm[k] - v;                      // exclusive
    if (k == NBUCK - 1) bucketstart[NBUCK] = sm[k];  // = EPLUS
  }
}

// ---- pass C: scatter edges into bucket-grouped order (LDS atomics only) ----
__global__ __launch_bounds__(256) void k_pC(const int* __restrict__ ei,
                                            const int* __restrict__ M,
                                            const int* __restrict__ bucketstart,
                                            uint* __restrict__ part) {
  __shared__ int lbase[NBUCK];
  __shared__ int lc[NBUCK];
  for (int k = threadIdx.x; k < NBUCK; k += 256) {
    lbase[k] = bucketstart[k] + M[blockIdx.x * NBUCK + k];
    lc[k] = 0;
  }
  __syncthreads();
  int lo = blockIdx.x * PCHUNK;
  int hi = lo + PCHUNK; if (hi > EPLUS) hi = EPLUS;
  for (int e = lo + threadIdx.x; e < hi; e += 256) {
    int src, dst;
    if (e < N_EDGES) { src = ei[e]; dst = ei[N_EDGES + e]; }
    else { src = dst = e - N_EDGES; }
    int b = dst >> 6;
    int p = lbase[b] + atomicAdd(&lc[b], 1);
    part[p] = (uint)src | ((uint)dst << 16);   // both ids < 2^16
  }
}

// ---- pass D: per-bucket fine CSR (64 dsts) via LDS counters + wave scan ----
__global__ __launch_bounds__(256) void k_pD(const uint* __restrict__ part,
                                            const int* __restrict__ bucketstart,
                                            int* __restrict__ rowstart,
                                            int* __restrict__ col) {
  __shared__ int dcnt[64], dstart[64], dc2[64];
  int b = blockIdx.x;
  int n0 = bucketstart[b], n1 = bucketstart[b + 1];
  int t = threadIdx.x;
  if (t < 64) { dcnt[t] = 0; dc2[t] = 0; }
  __syncthreads();
  for (int i = n0 + t; i < n1; i += 256)
    atomicAdd(&dcnt[(part[i] >> 16) & 63], 1);
  __syncthreads();
  if (t < 64) {
    int v = dcnt[t];
    int run = v;
    #pragma unroll
    for (int off = 1; off < 64; off <<= 1) {
      int u = __shfl_up(run, off);
      if (t >= off) run += u;
    }
    dstart[t] = run - v;   // exclusive within bucket
    int node = b * 64 + t;
    if (node < N_NODES) rowstart[node] = n0 + run - v;
  }
  if (b == NBUCK - 1 && t == 0) rowstart[N_NODES] = n1;  // = EPLUS
  __syncthreads();
  for (int i = n0 + t; i < n1; i += 256) {
    uint pr = part[i];
    int loc = (pr >> 16) & 63;
    int pos = n0 + dstart[loc] + atomicAdd(&dc2[loc], 1);
    col[pos] = (int)(pr & 0xffffu);
  }
}

// Y = X @ W via v_mfma_f32_16x16x32_f16. Full-K staging: A as f16 k-pairs
// (64x128, stride-68), W pre-swizzled into 32 fragment-linear B-frags
// (conflict-free b128 reads). 4 waves x 16 rows x 8 col-tiles, 32 MFMA/wave.
// Epilogue from documented C/D mapping (col=lane&15, row=(lane>>4)*4+reg):
// per-head es/ed via 16-lane shfl reduce; h f16-pack via lane-pair shfl.
template<int XF16>
__global__ __launch_bounds__(256) void k_gemm_fused(const float* __restrict__ X,
                                                    const uint* __restrict__ X16,
                                                    const float* __restrict__ W,
                                                    const float* __restrict__ asrc,
                                                    const float* __restrict__ adst,
                                                    uint* __restrict__ hbu,
                                                    float* __restrict__ es,
                                                    float* __restrict__ ed) {
  __shared__ uint As[64][68];      // [row][kpair 0..63] (17.4KB)
  __shared__ uint Bf[32 * 256];    // [(t*4+kb)*256 + lane*4 + u] (32KB)
  int tid = threadIdx.x;
  int lane = tid & 63;
  int wv = tid >> 6;
  int r0 = blockIdx.x * 64;

  // ---- stage A (full 64 rows x K=128) ----
  if (XF16) {
    #pragma unroll
    for (int i = 0; i < 4; ++i) {
      int q = tid + 256 * i;         // uint4 index, 16 per row
      int row = q >> 4;
      int u4 = q & 15;
      int gr = r0 + row;
      uint4 v = make_uint4(0u, 0u, 0u, 0u);
      if (gr < N_NODES) v = *(const uint4*)&X16[(size_t)gr * 64 + u4 * 4];
      *(uint4*)&As[row][u4 * 4] = v;
    }
  } else {
    #pragma unroll
    for (int i = 0; i < 8; ++i) {
      int q = tid + 256 * i;         // float4 index, 32 per row
      int row = q >> 5;
      int f4 = q & 31;
      int gr = r0 + row;
      float4 v = make_float4(0.f, 0.f, 0.f, 0.f);
      if (gr < N_NODES) v = *(const float4*)&X[(size_t)gr * 128 + f4 * 4];
      As[row][f4 * 2 + 0] = pkrn(v.x, v.y);
      As[row][f4 * 2 + 1] = pkrn(v.z, v.w);
    }
  }
  // ---- stage B fragments: frag f=t*4+kb; lane holds W[k0..k0+7][c],
  //      k0 = kb*32+(lane>>4)*8, c = t*16+(lane&15), packed as 4 k-pair uints ----
  #pragma unroll
  for (int i = 0; i < 8; ++i) {
    int f = wv + 4 * i;              // 0..31
    int t = f >> 2, kb = f & 3;
    int c = t * 16 + (lane & 15);
    int k0 = kb * 32 + (lane >> 4) * 8;
    const float* wp = &W[(size_t)k0 * 128 + c];
    uint4 b;
    b.x = pkrn(wp[0],   wp[128]);
    b.y = pkrn(wp[256], wp[384]);
    b.z = pkrn(wp[512], wp[640]);
    b.w = pkrn(wp[768], wp[896]);
    *(uint4*)&Bf[f * 256 + lane * 4] = b;
  }
  __syncthreads();

  // ---- MFMA main: wave owns rows rb..rb+15, all 128 cols ----
  int rb = wv * 16;
  f32x4 acc[8];
  #pragma unroll
  for (int t = 0; t < 8; ++t) acc[t] = (f32x4){0.f, 0.f, 0.f, 0.f};
  #pragma unroll
  for (int kb = 0; kb < 4; ++kb) {
    uint4 a4 = *(const uint4*)&As[rb + (lane & 15)][kb * 16 + (lane >> 4) * 4];
    f16x8 af; __builtin_memcpy(&af, &a4, 16);
    #pragma unroll
    for (int t = 0; t < 8; ++t) {
      uint4 b4 = *(const uint4*)&Bf[(t * 4 + kb) * 256 + lane * 4];
      f16x8 bfr; __builtin_memcpy(&bfr, &b4, 16);
      acc[t] = __builtin_amdgcn_mfma_f32_16x16x32_f16(af, bfr, acc[t], 0, 0, 0);
    }
  }

  // ---- epilogue ----
  // lane holds rows rb+(lane>>4)*4+j, cols c_t = t*16+(lane&15); head(c_t)=t>>1
  float asv[8], adv[8];
  #pragma unroll
  for (int t = 0; t < 8; ++t) {
    asv[t] = asrc[t * 16 + (lane & 15)];
    adv[t] = adst[t * 16 + (lane & 15)];
  }
  #pragma unroll
  for (int j = 0; j < 4; ++j) {
    int row = r0 + rb + (lane >> 4) * 4 + j;
    // per-head partial dots
    float ps[4], pd[4];
    #pragma unroll
    for (int m = 0; m < 4; ++m) {
      ps[m] = fmaf(acc[2 * m][j], asv[2 * m], acc[2 * m + 1][j] * asv[2 * m + 1]);
      pd[m] = fmaf(acc[2 * m][j], adv[2 * m], acc[2 * m + 1][j] * adv[2 * m + 1]);
    }
    #pragma unroll
    for (int off = 1; off < 16; off <<= 1) {
      #pragma unroll
      for (int m = 0; m < 4; ++m) {
        ps[m] += __shfl_xor(ps[m], off);
        pd[m] += __shfl_xor(pd[m], off);
      }
    }
    // h f16 pack: lane pairs share adjacent cols
    #pragma unroll
    for (int t = 0; t < 8; ++t) {
      float other = __shfl_xor(acc[t][j], 1);
      if (!(lane & 1) && row < N_NODES) {
        hbu[(size_t)row * 64 + t * 8 + ((lane & 15) >> 1)] = pkrn(acc[t][j], other);
      }
    }
    if ((lane & 15) == 0 && row < N_NODES) {
      #pragma unroll
      for (int m = 0; m < 4; ++m) {
        es[row * 4 + m] = ps[m];
        ed[row * 4 + m] = pd[m];
      }
    }
  }
}

// one wave per destination node. Phase A: lanes parallel over <=64 edges,
// exp-weights computed once per edge, stashed in LDS, denominator per-lane
// float4. Phase B: 16 lanes own 8 channels of one edge (uint4 = 8 f16);
// 16 edges per iteration = 4 independent dwordx4 gathers in flight (MLP);
// channel-pairs across edge pairs built with v_perm_b32 and multiplied with
// one v_dot2_f32_f16 per channel. Padded slots have w=0 (contribute nothing).
// wf16=1: write f16-packed output (layer-1 intermediate).
__global__ __launch_bounds__(256) void k_attn(const uint* __restrict__ hb,
                                              const float* __restrict__ es,
                                              const float* __restrict__ ed,
                                              const int* __restrict__ rowstart,
                                              const int* __restrict__ col,
                                              const float* __restrict__ bias,
                                              float* __restrict__ outp,
                                              uint* __restrict__ out16,
                                              int do_relu, int wf16) {
  __shared__ float swv[4][4 * 68];   // [wave][head*68 + edge]
  __shared__ int   ssc[4][64];       // [wave][edge] = src<<8 (byte offset of h row)
  int lane = threadIdx.x & 63;
  int wv = threadIdx.x >> 6;
  int n = blockIdx.x * 4 + wv;
  if (n >= N_NODES) return;
  int s = rowstart[n], t = rowstart[n + 1];
  int sub = lane & 15;         // channel-group owner (8 channels)
  int esel = lane >> 4;        // edge-in-group selector (0..3)
  int head2 = sub >> 2;        // head of this lane's 8 channels
  float4 edv = *(const float4*)&ed[n * 4];
  const char* hbb = (const char*)hb + (uint)sub * 16u;   // lane's 16B slice
  const char* esb = (const char*)es;
  float* wv0 = swv[wv];
  int* sc0 = ssc[wv];

  float4 denv = make_float4(0.f, 0.f, 0.f, 0.f);
  float acc[8];
  #pragma unroll
  for (int j = 0; j < 8; ++j) acc[j] = 0.f;

  for (int base = s; base < t; base += 64) {
    int nthis = t - base; if (nthis > 64) nthis = 64;
    int npad = (nthis + 15) & ~15;
    // ---- phase A ----
    if (lane < nthis) {
      int sc = col[base + lane];
      float4 esv = *(const float4*)(esb + ((uint)sc << 4));
      float w0 = __expf(lrelu(esv.x + edv.x));
      float w1 = __expf(lrelu(esv.y + edv.y));
      float w2 = __expf(lrelu(esv.z + edv.z));
      float w3 = __expf(lrelu(esv.w + edv.w));
      denv.x += w0; denv.y += w1; denv.z += w2; denv.w += w3;
      wv0[0 * 68 + lane] = w0;
      wv0[1 * 68 + lane] = w1;
      wv0[2 * 68 + lane] = w2;
      wv0[3 * 68 + lane] = w3;
      sc0[lane] = sc << 8;
    } else if (lane < npad) {
      wv0[0 * 68 + lane] = 0.f;
      wv0[1 * 68 + lane] = 0.f;
      wv0[2 * 68 + lane] = 0.f;
      wv0[3 * 68 + lane] = 0.f;
      sc0[lane] = 0;
    }
    asm volatile("s_waitcnt lgkmcnt(0)" ::: "memory");
    // ---- phase B: 16 edges per iteration (4 gathers in flight) ----
    __builtin_amdgcn_s_setprio(1);
    for (int i = 0; i < npad; i += 16) {
      int e0 = i + esel, e1 = e0 + 4, e2 = e0 + 8, e3 = e0 + 12;
      float w0 = wv0[head2 * 68 + e0];
      float w1 = wv0[head2 * 68 + e1];
      float w2 = wv0[head2 * 68 + e2];
      float w3 = wv0[head2 * 68 + e3];
      int so0 = sc0[e0], so1 = sc0[e1], so2 = sc0[e2], so3 = sc0[e3];
      uint4 q0 = *(const uint4*)(hbb + (uint)so0);
      uint4 q1 = *(const uint4*)(hbb + (uint)so1);
      uint4 q2 = *(const uint4*)(hbb + (uint)so2);
      uint4 q3 = *(const uint4*)(hbb + (uint)so3);
      uint wa = pkrtz(w0, w1);
      uint wb = pkrtz(w2, w3);
      acc[0] = fdot2(__builtin_amdgcn_perm(q1.x, q0.x, 0x05040100u), wa, acc[0]);
      acc[1] = fdot2(__builtin_amdgcn_perm(q1.x, q0.x, 0x07060302u), wa, acc[1]);
      acc[2] = fdot2(__builtin_amdgcn_perm(q1.y, q0.y, 0x05040100u), wa, acc[2]);
      acc[3] = fdot2(__builtin_amdgcn_perm(q1.y, q0.y, 0x07060302u), wa, acc[3]);
      acc[4] = fdot2(__builtin_amdgcn_perm(q1.z, q0.z, 0x05040100u), wa, acc[4]);
      acc[5] = fdot2(__builtin_amdgcn_perm(q1.z, q0.z, 0x07060302u), wa, acc[5]);
      acc[6] = fdot2(__builtin_amdgcn_perm(q1.w, q0.w, 0x05040100u), wa, acc[6]);
      acc[7] = fdot2(__builtin_amdgcn_perm(q1.w, q0.w, 0x07060302u), wa, acc[7]);
      acc[0] = fdot2(__builtin_amdgcn_perm(q3.x, q2.x, 0x05040100u), wb, acc[0]);
      acc[1] = fdot2(__builtin_amdgcn_perm(q3.x, q2.x, 0x07060302u), wb, acc[1]);
      acc[2] = fdot2(__builtin_amdgcn_perm(q3.y, q2.y, 0x05040100u), wb, acc[2]);
      acc[3] = fdot2(__builtin_amdgcn_perm(q3.y, q2.y, 0x07060302u), wb, acc[3]);
      acc[4] = fdot2(__builtin_amdgcn_perm(q3.z, q2.z, 0x05040100u), wb, acc[4]);
      acc[5] = fdot2(__builtin_amdgcn_perm(q3.z, q2.z, 0x07060302u), wb, acc[5]);
      acc[6] = fdot2(__builtin_amdgcn_perm(q3.w, q2.w, 0x05040100u), wb, acc[6]);
      acc[7] = fdot2(__builtin_amdgcn_perm(q3.w, q2.w, 0x07060302u), wb, acc[7]);
    }
    __builtin_amdgcn_s_setprio(0);
  }
  // reduce partial sums across the 4 edge-selector groups
  #pragma unroll
  for (int j = 0; j < 8; ++j) {
    acc[j] += __shfl_xor(acc[j], 16);
    acc[j] += __shfl_xor(acc[j], 32);
  }
  // reduce denominator across lanes (once per node)
  #pragma unroll
  for (int off = 1; off < 64; off <<= 1) {
    denv.x += __shfl_xor(denv.x, off);
    denv.y += __shfl_xor(denv.y, off);
    denv.z += __shfl_xor(denv.z, off);
    denv.w += __shfl_xor(denv.w, off);
  }
  float den = (head2 & 2) ? ((head2 & 1) ? denv.w : denv.z)
                          : ((head2 & 1) ? denv.y : denv.x);
  float inv = 1.0f / (den + 1e-16f);
  if (lane < 32) {
    int half = lane >> 4;            // 0 or 1
    int c = sub * 8 + half * 4;
    float4 bb = *(const float4*)&bias[c];
    float o0 = acc[half * 4 + 0] * inv + bb.x;
    float o1 = acc[half * 4 + 1] * inv + bb.y;
    float o2 = acc[half * 4 + 2] * inv + bb.z;
    float o3 = acc[half * 4 + 3] * inv + bb.w;
    if (do_relu) {
      o0 = fmaxf(o0, 0.f); o1 = fmaxf(o1, 0.f);
      o2 = fmaxf(o2, 0.f); o3 = fmaxf(o3, 0.f);
    }
    if (wf16) {
      uint2 p2;
      p2.x = pkrn(o0, o1);
      p2.y = pkrn(o2, o3);
      *(uint2*)&out16[(size_t)n * 64 + sub * 4 + half * 2] = p2;
    } else {
      *(float4*)&outp[(size_t)n * 128 + c] = make_float4(o0, o1, o2, o3);
    }
  }
}

// one block per graph: mean-pool (binary search on sorted batch) + 128->4 classifier
__global__ __launch_bounds__(128) void k_poolcls(const float* __restrict__ out2,
                                                 const int* __restrict__ batch,
                                                 const float* __restrict__ wc,
                                                 const float* __restrict__ bc,
                                                 float* __restrict__ y) {
  int b = blockIdx.x;
  int c = threadIdx.x;
  int lo = 0, hi = N_NODES;
  while (lo < hi) { int mid = (lo + hi) >> 1; if (batch[mid] < b) lo = mid + 1; else hi = mid; }
  int s = lo;
  lo = s; hi = N_NODES;
  while (lo < hi) { int mid = (lo + hi) >> 1; if (batch[mid] < b + 1) lo = mid + 1; else hi = mid; }
  int e = lo;
  float acc0 = 0.f, acc1 = 0.f, acc2 = 0.f, acc3 = 0.f;
  int nidx = s;
  for (; nidx + 4 <= e; nidx += 4) {
    acc0 += out2[(size_t)nidx * 128 + c];
    acc1 += out2[(size_t)(nidx + 1) * 128 + c];
    acc2 += out2[(size_t)(nidx + 2) * 128 + c];
    acc3 += out2[(size_t)(nidx + 3) * 128 + c];
  }
  for (; nidx < e; ++nidx) acc0 += out2[(size_t)nidx * 128 + c];
  float acc = (acc0 + acc1) + (acc2 + acc3);
  float cnt = (float)(e - s);
  float pooled = acc / fmaxf(cnt, 1.0f);
  float4 wrow = *(const float4*)&wc[c * 4];
  float wj[4] = {wrow.x, wrow.y, wrow.z, wrow.w};
  __shared__ float red[128];
  #pragma unroll
  for (int j = 0; j < 4; ++j) {
    red[c] = pooled * wj[j];
    __syncthreads();
    for (int off = 64; off > 0; off >>= 1) {
      if (c < off) red[c] += red[c + off];
      __syncthreads();
    }
    if (c == 0) y[b * 4 + j] = red[0] + bc[j];
    __syncthreads();
  }
}

extern "C" void kernel_launch(void* const* d_in, const int* in_sizes, int n_in,
                              void* d_out, int out_size, void* d_ws, size_t ws_size,
                              hipStream_t stream) {
  const float* x    = (const float*)d_in[0];
  const int*   ei   = (const int*)d_in[1];
  const int*   batch= (const int*)d_in[2];
  const float* w1   = (const float*)d_in[3];
  const float* as1  = (const float*)d_in[4];
  const float* ad1  = (const float*)d_in[5];
  const float* b1   = (const float*)d_in[6];
  const float* w2   = (const float*)d_in[7];
  const float* as2  = (const float*)d_in[8];
  const float* ad2  = (const float*)d_in[9];
  const float* b2   = (const float*)d_in[10];
  const float* wc   = (const float*)d_in[11];
  const float* bc   = (const float*)d_in[12];
  float* y = (float*)d_out;

  char* ws = (char*)d_ws;
  size_t o = 0;
  auto take = [&](size_t bytes) { void* p = ws + o; o = (o + bytes + 255) & ~(size_t)255; return p; };
  uint*  hbu      = (uint*)take((size_t)N_NODES * 64 * 4);        // f16 h, packed 2/word
  uint*  h1u      = (uint*)take((size_t)N_NODES * 64 * 4);        // f16 layer-1 output
  float* obuf     = (float*)take((size_t)N_NODES * HCH * 4);      // fp32 layer-2 output
  float* es       = (float*)take((size_t)N_NODES * 4 * 4);
  float* ed       = (float*)take((size_t)N_NODES * 4 * 4);
  int*   M        = (int*)take((size_t)NSB * NBUCK * 4);          // per-block bucket hist/prefix
  int*   tot      = (int*)take((size_t)NBUCK * 4);
  int*   bstart   = (int*)take((size_t)(NBUCK + 1) * 4);
  uint*  part     = (uint*)take((size_t)EPLUS * 4);               // bucket-grouped packed edges
  int*   rowstart = (int*)take((size_t)(N_NODES + 1) * 4);
  int*   col      = (int*)take((size_t)EPLUS * 4);

  const int GW = N_NODES / 4;               // 12500 wave-per-node
  const int GG = (N_NODES + 63) / 64;       // 782 gemm blocks

  // ---- CSR build (no global returning atomics; scan parallel across CUs) ----
  k_pA<<<NSB, 256, 0, stream>>>(ei, M);
  k_pB1<<<NBUCK, 256, 0, stream>>>(M, tot);
  k_pB2<<<1, 1024, 0, stream>>>(tot, bstart);
  k_pC<<<NSB, 256, 0, stream>>>(ei, M, bstart, part);
  k_pD<<<NBUCK, 256, 0, stream>>>(part, bstart, rowstart, col);

  // ---- layer 1 ----
  k_gemm_fused<0><<<GG, 256, 0, stream>>>(x, nullptr, w1, as1, ad1, hbu, es, ed);
  k_attn<<<GW, 256, 0, stream>>>(hbu, es, ed, rowstart, col, b1, obuf, h1u, 1, 1);

  // ---- layer 2 (X from f16 layer-1 output) ----
  k_gemm_fused<1><<<GG, 256, 0, stream>>>(nullptr, h1u, w2, as2, ad2, hbu, es, ed);
  k_attn<<<GW, 256, 0, stream>>>(hbu, es, ed, rowstart, col, b2, obuf, h1u, 0, 0);

  // ---- pool + classifier ----
  k_poolcls<<<NB, 128, 0, stream>>>(obuf, batch, wc, bc, y);
}

// Round 18
// 216.315 us; speedup vs baseline: 1.4672x; 1.0116x over previous
//
#include <hip/hip_runtime.h>
#include <hip/hip_fp16.h>

#define N_NODES 50000
#define N_EDGES 1600000
#define EPLUS   1650000   // edges + self loops
#define HCH 128           // hidden channels (H*C)
#define NB 512            // graphs
#define NCLS 4
#define NBUCK 782         // ceil(N_NODES/64); bucket = dst>>6
#define NSB 256           // scatter blocks for passes A/C
#define PCHUNK 6446       // ceil(EPLUS/NSB)

typedef unsigned int uint;
typedef __attribute__((ext_vector_type(8))) _Float16 f16x8;
typedef __attribute__((ext_vector_type(4))) float f32x4;

__device__ __forceinline__ float lrelu(float v) { return v > 0.f ? v : 0.2f * v; }

// D = a.lo*b.lo + a.hi*b.hi + c  (f16 pairs, f32 accumulate)
__device__ __forceinline__ float fdot2(uint a, uint b, float c) {
  asm("v_dot2_f32_f16 %0, %1, %2, %0" : "+v"(c) : "v"(a), "v"(b));
  return c;
}

// pack two f32 -> two f16 (RTZ) in one VGPR
__device__ __forceinline__ uint pkrtz(float a, float b) {
  auto v = __builtin_amdgcn_cvt_pkrtz(a, b);
  uint r;
  __builtin_memcpy(&r, &v, 4);
  return r;
}

// pack two f32 -> two f16 (RNE)
__device__ __forceinline__ uint pkrn(float a, float b) {
  return (uint)__half_as_ushort(__float2half_rn(a)) |
         ((uint)__half_as_ushort(__float2half_rn(b)) << 16);
}

// ---- pass A: per-block bucket histogram (LDS atomics only) ----
__global__ __launch_bounds__(256) void k_pA(const int* __restrict__ ei,
                                            int* __restrict__ M) {
  __shared__ int lh[NBUCK];
  for (int k = threadIdx.x; k < NBUCK; k += 256) lh[k] = 0;
  __syncthreads();
  int lo = blockIdx.x * PCHUNK;
  int hi = lo + PCHUNK; if (hi > EPLUS) hi = EPLUS;
  for (int e = lo + threadIdx.x; e < hi; e += 256) {
    int dst = (e < N_EDGES) ? ei[N_EDGES + e] : (e - N_EDGES);
    atomicAdd(&lh[dst >> 6], 1);
  }
  __syncthreads();
  for (int k = threadIdx.x; k < NBUCK; k += 256)
    M[blockIdx.x * NBUCK + k] = lh[k];
}

// ---- pass B1: per-bucket scan over the NSB block-counts (one block/bucket) ----
__global__ __launch_bounds__(256) void k_pB1(int* __restrict__ M,
                                             int* __restrict__ tot) {
  __shared__ int sm[256];
  int k = blockIdx.x;            // bucket
  int t = threadIdx.x;           // scatter-block index
  int v = M[t * NBUCK + k];
  sm[t] = v;
  __syncthreads();
  for (int off = 1; off < 256; off <<= 1) {
    int u = (t >= off) ? sm[t - off] : 0;
    __syncthreads();
    sm[t] += u;
    __syncthreads();
  }
  M[t * NBUCK + k] = sm[t] - v;  // within-bucket, over-blocks exclusive prefix
  if (t == 255) tot[k] = sm[255];
}

// ---- pass B2: bucket exclusive scan over 782 totals (1 small block-scan) ----
__global__ __launch_bounds__(1024) void k_pB2(const int* __restrict__ tot,
                                              int* __restrict__ bucketstart) {
  __shared__ int sm[1024];
  int k = threadIdx.x;
  int v = (k < NBUCK) ? tot[k] : 0;
  sm[k] = v;
  __syncthreads();
  for (int off = 1; off < 1024; off <<= 1) {
    int u = (k >= off) ? sm[k - off] : 0;
    __syncthreads();
    sm[k] += u;
    __syncthreads();
  }
  if (k < NBUCK) {
    bucketstart[k] = sm[k] - v;                      // exclusive
    if (k == NBUCK - 1) bucketstart[NBUCK] = sm[k];  // = EPLUS
  }
}

// ---- pass C: scatter edges into bucket-grouped order (LDS atomics only) ----
__global__ __launch_bounds__(256) void k_pC(const int* __restrict__ ei,
                                            const int* __restrict__ M,
                                            const int* __restrict__ bucketstart,
                                            uint* __restrict__ part) {
  __shared__ int lbase[NBUCK];
  __shared__ int lc[NBUCK];
  for (int k = threadIdx.x; k < NBUCK; k += 256) {
    lbase[k] = bucketstart[k] + M[blockIdx.x * NBUCK + k];
    lc[k] = 0;
  }
  __syncthreads();
  int lo = blockIdx.x * PCHUNK;
  int hi = lo + PCHUNK; if (hi > EPLUS) hi = EPLUS;
  for (int e = lo + threadIdx.x; e < hi; e += 256) {
    int src, dst;
    if (e < N_EDGES) { src = ei[e]; dst = ei[N_EDGES + e]; }
    else { src = dst = e - N_EDGES; }
    int b = dst >> 6;
    int p = lbase[b] + atomicAdd(&lc[b], 1);
    part[p] = (uint)src | ((uint)dst << 16);   // both ids < 2^16
  }
}

// ---- fused pass D + layer-1 GEMM (disjoint inputs; overlapped in one dispatch).
// odd blocks:  pD for bucket b = bid>>1 (col stores src<<8, pre-shifted for attn)
// even blocks: MFMA gemm for row-tile (bid>>1)*64 (X fp32 path, layer 1)
__global__ __launch_bounds__(256) void k_pD_gemm(const uint* __restrict__ part,
                                                 const int* __restrict__ bucketstart,
                                                 int* __restrict__ rowstart,
                                                 int* __restrict__ col,
                                                 const float* __restrict__ X,
                                                 const float* __restrict__ W,
                                                 const float* __restrict__ asrc,
                                                 const float* __restrict__ adst,
                                                 uint* __restrict__ hbu,
                                                 float* __restrict__ es,
                                                 float* __restrict__ ed) {
  __shared__ char smem[50176];     // union: pD (768B) | gemm As(17408)+Bf(32768)
  int tid = threadIdx.x;
  if (blockIdx.x & 1) {
    // ================= pass D =================
    int* dcnt   = (int*)smem;
    int* dstart = dcnt + 64;
    int* dc2    = dstart + 64;
    int b = blockIdx.x >> 1;
    int n0 = bucketstart[b], n1 = bucketstart[b + 1];
    int t = tid;
    if (t < 64) { dcnt[t] = 0; dc2[t] = 0; }
    __syncthreads();
    for (int i = n0 + t; i < n1; i += 256)
      atomicAdd(&dcnt[(part[i] >> 16) & 63], 1);
    __syncthreads();
    if (t < 64) {
      int v = dcnt[t];
      int run = v;
      #pragma unroll
      for (int off = 1; off < 64; off <<= 1) {
        int u = __shfl_up(run, off);
        if (t >= off) run += u;
      }
      dstart[t] = run - v;   // exclusive within bucket
      int node = b * 64 + t;
      if (node < N_NODES) rowstart[node] = n0 + run - v;
    }
    if (b == NBUCK - 1 && t == 0) rowstart[N_NODES] = n1;  // = EPLUS
    __syncthreads();
    for (int i = n0 + t; i < n1; i += 256) {
      uint pr = part[i];
      int loc = (pr >> 16) & 63;
      int pos = n0 + dstart[loc] + atomicAdd(&dc2[loc], 1);
      col[pos] = (int)((pr & 0xffffu) << 8);   // pre-shifted (byte offset of h row)
    }
  } else {
    // ================= layer-1 GEMM (MFMA) =================
    uint (*As)[68] = (uint(*)[68])smem;          // [row][kpair]
    uint* Bf = (uint*)(smem + 17408);            // 32 B-frags, fragment-linear
    int lane = tid & 63;
    int wv = tid >> 6;
    int r0 = (blockIdx.x >> 1) * 64;

    #pragma unroll
    for (int i = 0; i < 8; ++i) {
      int q = tid + 256 * i;         // float4 index, 32 per row
      int row = q >> 5;
      int f4 = q & 31;
      int gr = r0 + row;
      float4 v = make_float4(0.f, 0.f, 0.f, 0.f);
      if (gr < N_NODES) v = *(const float4*)&X[(size_t)gr * 128 + f4 * 4];
      As[row][f4 * 2 + 0] = pkrn(v.x, v.y);
      As[row][f4 * 2 + 1] = pkrn(v.z, v.w);
    }
    #pragma unroll
    for (int i = 0; i < 8; ++i) {
      int f = wv + 4 * i;              // 0..31
      int t = f >> 2, kb = f & 3;
      int c = t * 16 + (lane & 15);
      int k0 = kb * 32 + (lane >> 4) * 8;
      const float* wp = &W[(size_t)k0 * 128 + c];
      uint4 b;
      b.x = pkrn(wp[0],   wp[128]);
      b.y = pkrn(wp[256], wp[384]);
      b.z = pkrn(wp[512], wp[640]);
      b.w = pkrn(wp[768], wp[896]);
      *(uint4*)&Bf[f * 256 + lane * 4] = b;
    }
    __syncthreads();

    int rb = wv * 16;
    f32x4 acc[8];
    #pragma unroll
    for (int t = 0; t < 8; ++t) acc[t] = (f32x4){0.f, 0.f, 0.f, 0.f};
    #pragma unroll
    for (int kb = 0; kb < 4; ++kb) {
      uint4 a4 = *(const uint4*)&As[rb + (lane & 15)][kb * 16 + (lane >> 4) * 4];
      f16x8 af; __builtin_memcpy(&af, &a4, 16);
      #pragma unroll
      for (int t = 0; t < 8; ++t) {
        uint4 b4 = *(const uint4*)&Bf[(t * 4 + kb) * 256 + lane * 4];
        f16x8 bfr; __builtin_memcpy(&bfr, &b4, 16);
        acc[t] = __builtin_amdgcn_mfma_f32_16x16x32_f16(af, bfr, acc[t], 0, 0, 0);
      }
    }

    float asv[8], adv[8];
    #pragma unroll
    for (int t = 0; t < 8; ++t) {
      asv[t] = asrc[t * 16 + (lane & 15)];
      adv[t] = adst[t * 16 + (lane & 15)];
    }
    #pragma unroll
    for (int j = 0; j < 4; ++j) {
      int row = r0 + rb + (lane >> 4) * 4 + j;
      float ps[4], pd[4];
      #pragma unroll
      for (int m = 0; m < 4; ++m) {
        ps[m] = fmaf(acc[2 * m][j], asv[2 * m], acc[2 * m + 1][j] * asv[2 * m + 1]);
        pd[m] = fmaf(acc[2 * m][j], adv[2 * m], acc[2 * m + 1][j] * adv[2 * m + 1]);
      }
      #pragma unroll
      for (int off = 1; off < 16; off <<= 1) {
        #pragma unroll
        for (int m = 0; m < 4; ++m) {
          ps[m] += __shfl_xor(ps[m], off);
          pd[m] += __shfl_xor(pd[m], off);
        }
      }
      #pragma unroll
      for (int t = 0; t < 8; ++t) {
        float other = __shfl_xor(acc[t][j], 1);
        if (!(lane & 1) && row < N_NODES) {
          hbu[(size_t)row * 64 + t * 8 + ((lane & 15) >> 1)] = pkrn(acc[t][j], other);
        }
      }
      if ((lane & 15) == 0 && row < N_NODES) {
        #pragma unroll
        for (int m = 0; m < 4; ++m) {
          es[row * 4 + m] = ps[m];
          ed[row * 4 + m] = pd[m];
        }
      }
    }
  }
}

// Y = X @ W via v_mfma_f32_16x16x32_f16 (standalone, layer 2: X16 f16 input).
__global__ __launch_bounds__(256) void k_gemm_fused(const uint* __restrict__ X16,
                                                    const float* __restrict__ W,
                                                    const float* __restrict__ asrc,
                                                    const float* __restrict__ adst,
                                                    uint* __restrict__ hbu,
                                                    float* __restrict__ es,
                                                    float* __restrict__ ed) {
  __shared__ uint As[64][68];      // [row][kpair 0..63] (17.4KB)
  __shared__ uint Bf[32 * 256];    // [(t*4+kb)*256 + lane*4 + u] (32KB)
  int tid = threadIdx.x;
  int lane = tid & 63;
  int wv = tid >> 6;
  int r0 = blockIdx.x * 64;

  #pragma unroll
  for (int i = 0; i < 4; ++i) {
    int q = tid + 256 * i;         // uint4 index, 16 per row
    int row = q >> 4;
    int u4 = q & 15;
    int gr = r0 + row;
    uint4 v = make_uint4(0u, 0u, 0u, 0u);
    if (gr < N_NODES) v = *(const uint4*)&X16[(size_t)gr * 64 + u4 * 4];
    *(uint4*)&As[row][u4 * 4] = v;
  }
  #pragma unroll
  for (int i = 0; i < 8; ++i) {
    int f = wv + 4 * i;              // 0..31
    int t = f >> 2, kb = f & 3;
    int c = t * 16 + (lane & 15);
    int k0 = kb * 32 + (lane >> 4) * 8;
    const float* wp = &W[(size_t)k0 * 128 + c];
    uint4 b;
    b.x = pkrn(wp[0],   wp[128]);
    b.y = pkrn(wp[256], wp[384]);
    b.z = pkrn(wp[512], wp[640]);
    b.w = pkrn(wp[768], wp[896]);
    *(uint4*)&Bf[f * 256 + lane * 4] = b;
  }
  __syncthreads();

  int rb = wv * 16;
  f32x4 acc[8];
  #pragma unroll
  for (int t = 0; t < 8; ++t) acc[t] = (f32x4){0.f, 0.f, 0.f, 0.f};
  #pragma unroll
  for (int kb = 0; kb < 4; ++kb) {
    uint4 a4 = *(const uint4*)&As[rb + (lane & 15)][kb * 16 + (lane >> 4) * 4];
    f16x8 af; __builtin_memcpy(&af, &a4, 16);
    #pragma unroll
    for (int t = 0; t < 8; ++t) {
      uint4 b4 = *(const uint4*)&Bf[(t * 4 + kb) * 256 + lane * 4];
      f16x8 bfr; __builtin_memcpy(&bfr, &b4, 16);
      acc[t] = __builtin_amdgcn_mfma_f32_16x16x32_f16(af, bfr, acc[t], 0, 0, 0);
    }
  }

  float asv[8], adv[8];
  #pragma unroll
  for (int t = 0; t < 8; ++t) {
    asv[t] = asrc[t * 16 + (lane & 15)];
    adv[t] = adst[t * 16 + (lane & 15)];
  }
  #pragma unroll
  for (int j = 0; j < 4; ++j) {
    int row = r0 + rb + (lane >> 4) * 4 + j;
    float ps[4], pd[4];
    #pragma unroll
    for (int m = 0; m < 4; ++m) {
      ps[m] = fmaf(acc[2 * m][j], asv[2 * m], acc[2 * m + 1][j] * asv[2 * m + 1]);
      pd[m] = fmaf(acc[2 * m][j], adv[2 * m], acc[2 * m + 1][j] * adv[2 * m + 1]);
    }
    #pragma unroll
    for (int off = 1; off < 16; off <<= 1) {
      #pragma unroll
      for (int m = 0; m < 4; ++m) {
        ps[m] += __shfl_xor(ps[m], off);
        pd[m] += __shfl_xor(pd[m], off);
      }
    }
    #pragma unroll
    for (int t = 0; t < 8; ++t) {
      float other = __shfl_xor(acc[t][j], 1);
      if (!(lane & 1) && row < N_NODES) {
        hbu[(size_t)row * 64 + t * 8 + ((lane & 15) >> 1)] = pkrn(acc[t][j], other);
      }
    }
    if ((lane & 15) == 0 && row < N_NODES) {
      #pragma unroll
      for (int m = 0; m < 4; ++m) {
        es[row * 4 + m] = ps[m];
        ed[row * 4 + m] = pd[m];
      }
    }
  }
}

// one wave per destination node. Phase A: lanes parallel over <=64 edges,
// exp-weights computed once per edge, stashed in LDS, denominator per-lane
// float4. Phase B: 16 lanes own 8 channels of one edge (uint4 = 8 f16);
// 16 edges per iteration = 4 independent dwordx4 gathers in flight (MLP).
// col[] is pre-shifted (src<<8). wf16=1: write f16-packed output.
__global__ __launch_bounds__(256) void k_attn(const uint* __restrict__ hb,
                                              const float* __restrict__ es,
                                              const float* __restrict__ ed,
                                              const int* __restrict__ rowstart,
                                              const int* __restrict__ col,
                                              const float* __restrict__ bias,
                                              float* __restrict__ outp,
                                              uint* __restrict__ out16,
                                              int do_relu, int wf16) {
  __shared__ float swv[4][4 * 68];   // [wave][head*68 + edge]
  __shared__ int   ssc[4][64];       // [wave][edge] = src<<8 (byte offset of h row)
  int lane = threadIdx.x & 63;
  int wv = threadIdx.x >> 6;
  int n = blockIdx.x * 4 + wv;
  if (n >= N_NODES) return;
  int s = rowstart[n], t = rowstart[n + 1];
  int sub = lane & 15;         // channel-group owner (8 channels)
  int esel = lane >> 4;        // edge-in-group selector (0..3)
  int head2 = sub >> 2;        // head of this lane's 8 channels
  float4 edv = *(const float4*)&ed[n * 4];
  const char* hbb = (const char*)hb + (uint)sub * 16u;   // lane's 16B slice
  const char* esb = (const char*)es;
  float* wv0 = swv[wv];
  int* sc0 = ssc[wv];

  float4 denv = make_float4(0.f, 0.f, 0.f, 0.f);
  float acc[8];
  #pragma unroll
  for (int j = 0; j < 8; ++j) acc[j] = 0.f;

  for (int base = s; base < t; base += 64) {
    int nthis = t - base; if (nthis > 64) nthis = 64;
    int npad = (nthis + 15) & ~15;
    // ---- phase A ----
    if (lane < nthis) {
      int so = col[base + lane];         // src<<8
      float4 esv = *(const float4*)(esb + ((uint)so >> 4));
      float w0 = __expf(lrelu(esv.x + edv.x));
      float w1 = __expf(lrelu(esv.y + edv.y));
      float w2 = __expf(lrelu(esv.z + edv.z));
      float w3 = __expf(lrelu(esv.w + edv.w));
      denv.x += w0; denv.y += w1; denv.z += w2; denv.w += w3;
      wv0[0 * 68 + lane] = w0;
      wv0[1 * 68 + lane] = w1;
      wv0[2 * 68 + lane] = w2;
      wv0[3 * 68 + lane] = w3;
      sc0[lane] = so;
    } else if (lane < npad) {
      wv0[0 * 68 + lane] = 0.f;
      wv0[1 * 68 + lane] = 0.f;
      wv0[2 * 68 + lane] = 0.f;
      wv0[3 * 68 + lane] = 0.f;
      sc0[lane] = 0;
    }
    asm volatile("s_waitcnt lgkmcnt(0)" ::: "memory");
    // ---- phase B: 16 edges per iteration (4 gathers in flight) ----
    __builtin_amdgcn_s_setprio(1);
    for (int i = 0; i < npad; i += 16) {
      int e0 = i + esel, e1 = e0 + 4, e2 = e0 + 8, e3 = e0 + 12;
      float w0 = wv0[head2 * 68 + e0];
      float w1 = wv0[head2 * 68 + e1];
      float w2 = wv0[head2 * 68 + e2];
      float w3 = wv0[head2 * 68 + e3];
      int so0 = sc0[e0], so1 = sc0[e1], so2 = sc0[e2], so3 = sc0[e3];
      uint4 q0 = *(const uint4*)(hbb + (uint)so0);
      uint4 q1 = *(const uint4*)(hbb + (uint)so1);
      uint4 q2 = *(const uint4*)(hbb + (uint)so2);
      uint4 q3 = *(const uint4*)(hbb + (uint)so3);
      uint wa = pkrtz(w0, w1);
      uint wb = pkrtz(w2, w3);
      acc[0] = fdot2(__builtin_amdgcn_perm(q1.x, q0.x, 0x05040100u), wa, acc[0]);
      acc[1] = fdot2(__builtin_amdgcn_perm(q1.x, q0.x, 0x07060302u), wa, acc[1]);
      acc[2] = fdot2(__builtin_amdgcn_perm(q1.y, q0.y, 0x05040100u), wa, acc[2]);
      acc[3] = fdot2(__builtin_amdgcn_perm(q1.y, q0.y, 0x07060302u), wa, acc[3]);
      acc[4] = fdot2(__builtin_amdgcn_perm(q1.z, q0.z, 0x05040100u), wa, acc[4]);
      acc[5] = fdot2(__builtin_amdgcn_perm(q1.z, q0.z, 0x07060302u), wa, acc[5]);
      acc[6] = fdot2(__builtin_amdgcn_perm(q1.w, q0.w, 0x05040100u), wa, acc[6]);
      acc[7] = fdot2(__builtin_amdgcn_perm(q1.w, q0.w, 0x07060302u), wa, acc[7]);
      acc[0] = fdot2(__builtin_amdgcn_perm(q3.x, q2.x, 0x05040100u), wb, acc[0]);
      acc[1] = fdot2(__builtin_amdgcn_perm(q3.x, q2.x, 0x07060302u), wb, acc[1]);
      acc[2] = fdot2(__builtin_amdgcn_perm(q3.y, q2.y, 0x05040100u), wb, acc[2]);
      acc[3] = fdot2(__builtin_amdgcn_perm(q3.y, q2.y, 0x07060302u), wb, acc[3]);
      acc[4] = fdot2(__builtin_amdgcn_perm(q3.z, q2.z, 0x05040100u), wb, acc[4]);
      acc[5] = fdot2(__builtin_amdgcn_perm(q3.z, q2.z, 0x07060302u), wb, acc[5]);
      acc[6] = fdot2(__builtin_amdgcn_perm(q3.w, q2.w, 0x05040100u), wb, acc[6]);
      acc[7] = fdot2(__builtin_amdgcn_perm(q3.w, q2.w, 0x07060302u), wb, acc[7]);
    }
    __builtin_amdgcn_s_setprio(0);
  }
  // reduce partial sums across the 4 edge-selector groups
  #pragma unroll
  for (int j = 0; j < 8; ++j) {
    acc[j] += __shfl_xor(acc[j], 16);
    acc[j] += __shfl_xor(acc[j], 32);
  }
  // reduce denominator across lanes (once per node)
  #pragma unroll
  for (int off = 1; off < 64; off <<= 1) {
    denv.x += __shfl_xor(denv.x, off);
    denv.y += __shfl_xor(denv.y, off);
    denv.z += __shfl_xor(denv.z, off);
    denv.w += __shfl_xor(denv.w, off);
  }
  float den = (head2 & 2) ? ((head2 & 1) ? denv.w : denv.z)
                          : ((head2 & 1) ? denv.y : denv.x);
  float inv = 1.0f / (den + 1e-16f);
  if (lane < 32) {
    int half = lane >> 4;            // 0 or 1
    int c = sub * 8 + half * 4;
    float4 bb = *(const float4*)&bias[c];
    float o0 = acc[half * 4 + 0] * inv + bb.x;
    float o1 = acc[half * 4 + 1] * inv + bb.y;
    float o2 = acc[half * 4 + 2] * inv + bb.z;
    float o3 = acc[half * 4 + 3] * inv + bb.w;
    if (do_relu) {
      o0 = fmaxf(o0, 0.f); o1 = fmaxf(o1, 0.f);
      o2 = fmaxf(o2, 0.f); o3 = fmaxf(o3, 0.f);
    }
    if (wf16) {
      uint2 p2;
      p2.x = pkrn(o0, o1);
      p2.y = pkrn(o2, o3);
      *(uint2*)&out16[(size_t)n * 64 + sub * 4 + half * 2] = p2;
    } else {
      *(float4*)&outp[(size_t)n * 128 + c] = make_float4(o0, o1, o2, o3);
    }
  }
}

// one block per graph: mean-pool (binary search on sorted batch) + 128->4 classifier
__global__ __launch_bounds__(128) void k_poolcls(const float* __restrict__ out2,
                                                 const int* __restrict__ batch,
                                                 const float* __restrict__ wc,
                                                 const float* __restrict__ bc,
                                                 float* __restrict__ y) {
  int b = blockIdx.x;
  int c = threadIdx.x;
  int lo = 0, hi = N_NODES;
  while (lo < hi) { int mid = (lo + hi) >> 1; if (batch[mid] < b) lo = mid + 1; else hi = mid; }
  int s = lo;
  lo = s; hi = N_NODES;
  while (lo < hi) { int mid = (lo + hi) >> 1; if (batch[mid] < b + 1) lo = mid + 1; else hi = mid; }
  int e = lo;
  float acc0 = 0.f, acc1 = 0.f, acc2 = 0.f, acc3 = 0.f;
  int nidx = s;
  for (; nidx + 4 <= e; nidx += 4) {
    acc0 += out2[(size_t)nidx * 128 + c];
    acc1 += out2[(size_t)(nidx + 1) * 128 + c];
    acc2 += out2[(size_t)(nidx + 2) * 128 + c];
    acc3 += out2[(size_t)(nidx + 3) * 128 + c];
  }
  for (; nidx < e; ++nidx) acc0 += out2[(size_t)nidx * 128 + c];
  float acc = (acc0 + acc1) + (acc2 + acc3);
  float cnt = (float)(e - s);
  float pooled = acc / fmaxf(cnt, 1.0f);
  float4 wrow = *(const float4*)&wc[c * 4];
  float wj[4] = {wrow.x, wrow.y, wrow.z, wrow.w};
  __shared__ float red[128];
  #pragma unroll
  for (int j = 0; j < 4; ++j) {
    red[c] = pooled * wj[j];
    __syncthreads();
    for (int off = 64; off > 0; off >>= 1) {
      if (c < off) red[c] += red[c + off];
      __syncthreads();
    }
    if (c == 0) y[b * 4 + j] = red[0] + bc[j];
    __syncthreads();
  }
}

extern "C" void kernel_launch(void* const* d_in, const int* in_sizes, int n_in,
                              void* d_out, int out_size, void* d_ws, size_t ws_size,
                              hipStream_t stream) {
  const float* x    = (const float*)d_in[0];
  const int*   ei   = (const int*)d_in[1];
  const int*   batch= (const int*)d_in[2];
  const float* w1   = (const float*)d_in[3];
  const float* as1  = (const float*)d_in[4];
  const float* ad1  = (const float*)d_in[5];
  const float* b1   = (const float*)d_in[6];
  const float* w2   = (const float*)d_in[7];
  const float* as2  = (const float*)d_in[8];
  const float* ad2  = (const float*)d_in[9];
  const float* b2   = (const float*)d_in[10];
  const float* wc   = (const float*)d_in[11];
  const float* bc   = (const float*)d_in[12];
  float* y = (float*)d_out;

  char* ws = (char*)d_ws;
  size_t o = 0;
  auto take = [&](size_t bytes) { void* p = ws + o; o = (o + bytes + 255) & ~(size_t)255; return p; };
  uint*  hbu      = (uint*)take((size_t)N_NODES * 64 * 4);        // f16 h, packed 2/word
  uint*  h1u      = (uint*)take((size_t)N_NODES * 64 * 4);        // f16 layer-1 output
  float* obuf     = (float*)take((size_t)N_NODES * HCH * 4);      // fp32 layer-2 output
  float* es       = (float*)take((size_t)N_NODES * 4 * 4);
  float* ed       = (float*)take((size_t)N_NODES * 4 * 4);
  int*   M        = (int*)take((size_t)NSB * NBUCK * 4);          // per-block bucket hist/prefix
  int*   tot      = (int*)take((size_t)NBUCK * 4);
  int*   bstart   = (int*)take((size_t)(NBUCK + 1) * 4);
  uint*  part     = (uint*)take((size_t)EPLUS * 4);               // bucket-grouped packed edges
  int*   rowstart = (int*)take((size_t)(N_NODES + 1) * 4);
  int*   col      = (int*)take((size_t)EPLUS * 4);

  const int GW = N_NODES / 4;               // 12500 wave-per-node
  const int GG = (N_NODES + 63) / 64;       // 782 gemm blocks

  // ---- CSR build (coarse) ----
  k_pA<<<NSB, 256, 0, stream>>>(ei, M);
  k_pB1<<<NBUCK, 256, 0, stream>>>(M, tot);
  k_pB2<<<1, 1024, 0, stream>>>(tot, bstart);
  k_pC<<<NSB, 256, 0, stream>>>(ei, M, bstart, part);

  // ---- fused: fine CSR (pD) + layer-1 GEMM (disjoint inputs, one dispatch) ----
  k_pD_gemm<<<2 * GG, 256, 0, stream>>>(part, bstart, rowstart, col,
                                        x, w1, as1, ad1, hbu, es, ed);

  // ---- layer 1 attention ----
  k_attn<<<GW, 256, 0, stream>>>(hbu, es, ed, rowstart, col, b1, obuf, h1u, 1, 1);

  // ---- layer 2 ----
  k_gemm_fused<<<GG, 256, 0, stream>>>(h1u, w2, as2, ad2, hbu, es, ed);
  k_attn<<<GW, 256, 0, stream>>>(hbu, es, ed, rowstart, col, b2, obuf, h1u, 0, 0);

  // ---- pool + classifier ----
  k_poolcls<<<NB, 128, 0, stream>>>(obuf, batch, wc, bc, y);
}